// Round 4
// baseline (538.148 us; speedup 1.0000x reference)
//
#include <hip/hip_runtime.h>
#include <math.h>

#define HID   128
#define MAXN  100000
#define MAXE  300000
#define EVT   4096
#define NNODE 20000
#define NEDGE 320000

typedef unsigned short u16;
typedef __attribute__((ext_vector_type(8))) short bf16x8;
typedef __attribute__((ext_vector_type(4))) float f32x4;

// ---------------- workspace layout (bytes) ----------------
// PERSIST (weights)
#define OFF_WCATB     0u                    // 384*768 bf16 = 589824  ([w_ih | w_hh] concat)
#define OFF_WEB       589824u               // 128*256 bf16 = 65536
#define OFF_WALLB     655360u               // 768*128 bf16 = 196608
#define OFF_BALL      851968u               // 768 f32 = 3072
#define BASE2         855040u
// EVENT arena
#define OFF_HEAD_SRC  (BASE2 + 0u)          // MAXN i32 (0xFF init)
#define OFF_HEAD_DST  (BASE2 + 400128u)     // MAXN i32 (0xFF init)
#define OFF_CNT_SRC   (BASE2 + 800256u)     // MAXN i32 (0 init)
#define OFF_CNT_DST   (BASE2 + 1200384u)    // MAXN i32 (0 init)
#define OFF_CHAIN_SRC (BASE2 + 1600512u)    // EVT i32
#define OFF_CHAIN_DST (BASE2 + 1616896u)    // EVT i32
#define OFF_XHB       (BASE2 + 1703936u)    // 8192*768 bf16 = 12582912 (msg cols 0..640 | mem-bf16 cols 640..768)
#define OFF_HG        (BASE2 + 14286848u)   // 8192*128 f32 = 4194304 (f32 pre-update memory rows)
// NODE arena (disjoint; no aliasing needed)
#define OFF_XB        (BASE2 + 20000000u)   // 20000*128 bf16 = 5120000
#define OFF_QB        (BASE2 + 25120000u)   // 20000*768 bf16 = 30720000
#define OFF_SKIPF     (BASE2 + 55840000u)   // 20000*128 f32 = 10240000
#define OFF_DEG       (BASE2 + 66080000u)   // 20000 i32
#define OFF_OFFS      (BASE2 + 66160128u)   // 20001 i32
#define OFF_CURSOR    (BASE2 + 66240256u)   // 20000 i32
#define OFF_SORTED    (BASE2 + 66320384u)   // 320000 i32
#define OFF_SACCB     (BASE2 + 67600384u)   // 20000*256 bf16 = 10240000
// peak ~78.5 MB

__device__ __forceinline__ float sigmoidf_(float x) { return 1.f / (1.f + __expf(-x)); }
__device__ __forceinline__ u16 f2b(float f) {
    unsigned u = __float_as_uint(f);
    unsigned r = (u + 0x7fffu + ((u >> 16) & 1u)) >> 16;
    return (u16)r;
}
__device__ __forceinline__ float b2f(unsigned h) { return __uint_as_float(h << 16); }

// ---- fused weight prep: Wcat build + we convert + Wall build + deg zero + table clears ----
// sections: [0,1152) Wcat | [1152,1280) we | [1280,1359) deg | [1359,1743) Wall | [1743,2000) clears
__global__ void k_prep(const float* __restrict__ w_ih, const float* __restrict__ w_hh,
                       const float* __restrict__ we,
                       const float* __restrict__ wq, const float* __restrict__ wk_,
                       const float* __restrict__ wv, const float* __restrict__ wskip,
                       const float* __restrict__ bq, const float* __restrict__ bk,
                       const float* __restrict__ bv, const float* __restrict__ bskip,
                       u16* __restrict__ Wcatb, u16* __restrict__ we_b,
                       u16* __restrict__ Wallb, float* __restrict__ ball,
                       int* __restrict__ deg, char* __restrict__ zbase) {
    int b = blockIdx.x, t = threadIdx.x;
    if (b < 1152) {                     // Wcat: 384 rows x 768 cols
        int idx = b * 256 + t;
        int row = idx / 768, col = idx % 768;
        float v = (col < 640) ? w_ih[row * 640 + col] : w_hh[row * 128 + (col - 640)];
        Wcatb[idx] = f2b(v);
        return;
    }
    b -= 1152;
    if (b < 128) {                      // we: 128*256
        int i = b * 256 + t;
        we_b[i] = f2b(we[i]);
        return;
    }
    b -= 128;
    if (b < 79) {                       // deg zero
        int i = b * 256 + t;
        if (i < NNODE) deg[i] = 0;
        return;
    }
    b -= 79;
    if (b < 384) {                      // Wall build: 768*128
        int idx = b * 256 + t;
        int row = idx >> 7;
        int k = idx & 127;
        float v;
        if (row < 128)      v = wq[row * 128 + k];
        else if (row < 256) v = wk_[(row - 128) * 128 + k];
        else if (row < 384) v = wv[(row - 256) * 128 + k];
        else if (row < 512) v = wskip[(row - 384) * 128 + k];
        else {
            int j = row - 512;
            float a = 0.f;
            for (int t2 = 0; t2 < 128; t2++) a += wq[t2 * 128 + k] * we[t2 * 256 + j];
            v = a;
        }
        Wallb[row * 128 + k] = f2b(v);
        if (k == 0) {
            float bb;
            if (row < 128)      bb = bq[row];
            else if (row < 256) bb = bk[row - 128];
            else if (row < 384) bb = bv[row - 256];
            else if (row < 512) bb = bskip[row - 384];
            else { int j = row - 512; float a = 0.f; for (int t2 = 0; t2 < 128; t2++) a += bq[t2] * we[t2 * 256 + j]; bb = a; }
            ball[row] = bb;
        }
        return;
    }
    b -= 384;
    // table clears: heads (0xFF, 800256 B) then cnts (0, 800256 B), 16B chunks
    const int NFF = 50016;     // 800256/16
    uint4 ff = make_uint4(0xFFFFFFFFu, 0xFFFFFFFFu, 0xFFFFFFFFu, 0xFFFFFFFFu);
    uint4 zz = make_uint4(0u, 0u, 0u, 0u);
    int idx = b * 256 + t;
    int stride = 257 * 256;
    uint4* pff = (uint4*)zbase;
    uint4* pzz = (uint4*)(zbase + 800256);
    for (int i = idx; i < NFF; i += stride) pff[i] = ff;
    for (int i = idx; i < NFF; i += stride) pzz[i] = zz;
}

// ---- fused: messages (direct XHb/Hg write) + id tables/chains + dst-deg hist ----
__global__ void k_msg_tables(const int* __restrict__ et_ids, const int* __restrict__ src_ids,
                          const float* __restrict__ src_mask, const int* __restrict__ dst_ids,
                          const float* __restrict__ dst_mask, const int* __restrict__ ev_eids,
                          const float* __restrict__ ev_emb, const float* __restrict__ ev_mask,
                          const float* __restrict__ ev_ts, const float* __restrict__ memory,
                          const float* __restrict__ last_update, const float* __restrict__ time_w,
                          const float* __restrict__ time_b,
                          int* __restrict__ head_src, int* __restrict__ head_dst,
                          int* __restrict__ cnt_src, int* __restrict__ cnt_dst,
                          int* __restrict__ chain_src, int* __restrict__ chain_dst,
                          const int* __restrict__ eidx, int* __restrict__ deg,
                          u16* __restrict__ XHb, float* __restrict__ Hg) {
    int b = blockIdx.x, t = threadIdx.x;
    if (b >= EVT) {
        int bb = b - EVT;
        if (bb < 32) {                       // tables: 4096 events
            int i = bb * 128 + t;
            int s = src_ids[i], d = dst_ids[i];
            chain_src[i] = atomicExch(&head_src[s], i);
            atomicAdd(&cnt_src[s], 1);
            chain_dst[i] = atomicExch(&head_dst[d], i);
            atomicAdd(&cnt_dst[d], 1);
        } else {                             // deg hist: 320000 edges
            int j = (bb - 32) * 128 + t;
            atomicAdd(&deg[eidx[NEDGE + j]], 1);
        }
        return;
    }
    int i = b;
    int c = t;
    int et = et_ids[i];
    float sm = src_mask[i], dm = dst_mask[i], em = ev_mask[i], ts = ev_ts[i];
    int sid = src_ids[i], did = dst_ids[i], eid = ev_eids[i];
    float isnode = (et == 3 || et == 4) ? 1.f : 0.f;
    float rel = ts - last_update[eid] * dm;
    float tval = ts * isnode + rel * dm;
    float tse = __cosf(tval * time_w[c] + time_b[c]) * em;
    float typ = (float)et;
    float sv_raw = memory[(size_t)sid * HID + c];
    float dv_raw = memory[(size_t)did * HID + c];
    float sv = sv_raw * sm;
    float dv = dv_raw * dm;
    float ev = ev_emb[(size_t)i * HID + c];
    // Hg (f32 pre-update memory rows, for GRU h0)
    Hg[(size_t)i * HID + c] = sv_raw;
    Hg[(size_t)(EVT + i) * HID + c] = dv_raw;
    // src-side row: msg cols 0..640, memory-bf16 col 640..768
    u16* xs = XHb + (size_t)i * 768;
    xs[c] = f2b(typ * em); xs[128 + c] = f2b(sv * em); xs[256 + c] = f2b(dv * em);
    xs[384 + c] = f2b(tse * em); xs[512 + c] = f2b(ev * em);
    xs[640 + c] = f2b(sv_raw);
    // dst-side row
    u16* xd = XHb + (size_t)(EVT + i) * 768;
    xd[c] = f2b(typ * dm); xd[128 + c] = f2b(dv * dm); xd[256 + c] = f2b(sv * dm);
    xd[384 + c] = f2b(tse * dm); xd[512 + c] = f2b(ev * dm);
    xd[640 + c] = f2b(dv_raw);
}

// ---- fixup: rows whose id has cnt>1 recompute the group mean via chain walk ----
__global__ void k_fix(const int* __restrict__ src_ids, const int* __restrict__ dst_ids,
                      const int* __restrict__ head_src, const int* __restrict__ head_dst,
                      const int* __restrict__ chain_src, const int* __restrict__ chain_dst,
                      const int* __restrict__ cnt_src, const int* __restrict__ cnt_dst,
                      const int* __restrict__ et_ids, const float* __restrict__ src_mask,
                      const float* __restrict__ dst_mask, const int* __restrict__ ev_eids,
                      const float* __restrict__ ev_emb, const float* __restrict__ ev_mask,
                      const float* __restrict__ ev_ts, const float* __restrict__ memory,
                      const float* __restrict__ last_update, const float* __restrict__ time_w,
                      const float* __restrict__ time_b, u16* __restrict__ XHb) {
    int r = blockIdx.x, c = threadIdx.x;
    bool is_src = (r < EVT);
    int id = is_src ? src_ids[r] : dst_ids[r - EVT];
    int cnt = is_src ? cnt_src[id] : cnt_dst[id];
    if (cnt < 2) return;
    float own = memory[(size_t)id * HID + c];
    float tw = time_w[c], tb = time_b[c];
    float a0 = 0.f, a1 = 0.f, a2 = 0.f, a3 = 0.f, a4 = 0.f;
    int j = is_src ? head_src[id] : head_dst[id];
    for (int k = 0; k < cnt; ++k) {
        int et = et_ids[j];
        float sm = src_mask[j], dm = dst_mask[j], em = ev_mask[j], ts = ev_ts[j];
        int eid = ev_eids[j];
        float isnode = (et == 3 || et == 4) ? 1.f : 0.f;
        float rel = ts - last_update[eid] * dm;
        float tval = ts * isnode + rel * dm;
        float tse = __cosf(tval * tw + tb);
        float ev = ev_emb[(size_t)j * HID + c];
        float typ = (float)et;
        if (is_src) {
            float sv = own * sm;
            float dv = memory[(size_t)dst_ids[j] * HID + c] * dm;
            float tsm = tse * em;
            a0 += typ * em; a1 += sv * em; a2 += dv * em;
            a3 += tsm * em; a4 += ev * em;
            j = chain_src[j];
        } else {
            float dv = own * dm;
            float sv = memory[(size_t)src_ids[j] * HID + c] * sm;
            float tsm = tse * em;
            a0 += typ * dm; a1 += dv * dm; a2 += sv * dm;
            a3 += tsm * dm; a4 += ev * dm;
            j = chain_dst[j];
        }
    }
    float inv = 1.f / (float)cnt;
    u16* x = XHb + (size_t)r * 768;
    x[c] = f2b(a0 * inv); x[128 + c] = f2b(a1 * inv); x[256 + c] = f2b(a2 * inv);
    x[384 + c] = f2b(a3 * inv); x[512 + c] = f2b(a4 * inv);
}

// ---- shared MFMA K-pass: acc += A[128 strip, K] @ W[128 rows, K]^T (strided) ----
__device__ __forceinline__ void gate_pass(const u16* __restrict__ A, int lda,
                                          const u16* __restrict__ W, int ldw, int K,
                                          f32x4 acc[4][4], u16* Als, u16* Wls,
                                          int bm, int wm, int wn, int l15, int quad, int tid) {
    for (int k0 = 0; k0 < K; k0 += 32) {
#pragma unroll
        for (int h = 0; h < 2; ++h) {
            int ch = tid + h * 256;
            int row = ch >> 2, kc = (ch & 3) * 8;
            *(float4*)&Als[row * 40 + kc] = *(const float4*)(A + (size_t)(bm + row) * lda + k0 + kc);
            *(float4*)&Wls[row * 40 + kc] = *(const float4*)(W + (size_t)row * ldw + k0 + kc);
        }
        __syncthreads();
        bf16x8 af[4], bfr[4];
#pragma unroll
        for (int r = 0; r < 4; ++r)
            af[r] = *(const bf16x8*)&Als[(wm + r * 16 + l15) * 40 + quad * 8];
#pragma unroll
        for (int c2 = 0; c2 < 4; ++c2)
            bfr[c2] = *(const bf16x8*)&Wls[(wn + c2 * 16 + l15) * 40 + quad * 8];
#pragma unroll
        for (int r = 0; r < 4; ++r)
#pragma unroll
            for (int c2 = 0; c2 < 4; ++c2)
                acc[r][c2] = __builtin_amdgcn_mfma_f32_16x16x32_bf16(af[r], bfr[c2], acc[r][c2], 0, 0, 0);
        __syncthreads();
    }
}

// ---- fused gates GEMM + GRU + memory scatter ----
// r,z gates: single K=768 pass over [Xg|Hg_bf16] @ [w_ih|w_hh]^T.
// n gate: gi2 (K=640) and gh2 (K=128) separate (r multiplies gh2).
// 64 blocks (one 128-row strip each), all co-resident.
__global__ __launch_bounds__(256, 1) void k_gates(const u16* __restrict__ XHb,
        const u16* __restrict__ Wcat, const float* __restrict__ b_ih,
        const float* __restrict__ b_hh, const float* __restrict__ Hg,
        const int* __restrict__ src_ids, const int* __restrict__ dst_ids,
        const int* __restrict__ cnt_dst, float* __restrict__ memory) {
    __shared__ u16 Als[128 * 40];
    __shared__ u16 Wls[128 * 40];
    int tid = threadIdx.x;
    int bm = blockIdx.x * 128;
    int wave = tid >> 6, lane = tid & 63;
    int wm = (wave & 1) * 64, wn = (wave >> 1) * 64;
    int l15 = lane & 15, quad = lane >> 4;
    f32x4 acc_h[4][4] = {};   // gh2, then r*(gh2+b_hh2)
    f32x4 acc_a[4][4] = {};   // r pre-act, then z pre-act
    f32x4 acc_i[4][4] = {};   // gi2
    // Phase A: gh2 = Hg_bf16 @ w_hh[256:384]^T  (K=128)
    gate_pass(XHb + 640, 768, Wcat + (size_t)256 * 768 + 640, 768, 128,
              acc_h, Als, Wls, bm, wm, wn, l15, quad, tid);
    // Phase B: r pre-activation (K=768)
    gate_pass(XHb, 768, Wcat, 768, 768, acc_a, Als, Wls, bm, wm, wn, l15, quad, tid);
#pragma unroll
    for (int r = 0; r < 4; ++r)
#pragma unroll
        for (int c2 = 0; c2 < 4; ++c2) {
            int ncol = wn + c2 * 16 + l15;
            float bs0 = b_ih[ncol] + b_hh[ncol];
            float bh2 = b_hh[256 + ncol];
#pragma unroll
            for (int reg = 0; reg < 4; ++reg) {
                float rg = sigmoidf_(acc_a[r][c2][reg] + bs0);
                acc_h[r][c2][reg] = rg * (acc_h[r][c2][reg] + bh2);
                acc_a[r][c2][reg] = 0.f;
            }
        }
    // Phase C: z pre-activation (K=768)
    gate_pass(XHb, 768, Wcat + (size_t)128 * 768, 768, 768,
              acc_a, Als, Wls, bm, wm, wn, l15, quad, tid);
    // Phase D: gi2 (K=640)
    gate_pass(XHb, 768, Wcat + (size_t)256 * 768, 768, 640,
              acc_i, Als, Wls, bm, wm, wn, l15, quad, tid);
    // Epilogue: n, h, scatter (dst overrides src; src visible iff id never a dst)
#pragma unroll
    for (int r = 0; r < 4; ++r)
#pragma unroll
        for (int c2 = 0; c2 < 4; ++c2) {
            int ncol = wn + c2 * 16 + l15;
            float bz = b_ih[128 + ncol] + b_hh[128 + ncol];
            float bi2 = b_ih[256 + ncol];
#pragma unroll
            for (int reg = 0; reg < 4; ++reg) {
                int mrow = bm + wm + r * 16 + quad * 4 + reg;
                float z = sigmoidf_(acc_a[r][c2][reg] + bz);
                float n = tanhf(acc_i[r][c2][reg] + bi2 + acc_h[r][c2][reg]);
                float h0 = Hg[(size_t)mrow * HID + ncol];
                float h = (1.f - z) * n + z * h0;
                if (mrow < EVT) {
                    int sid = src_ids[mrow];
                    if (cnt_dst[sid] == 0) memory[(size_t)sid * HID + ncol] = h;
                } else {
                    int did = dst_ids[mrow - EVT];
                    memory[(size_t)did * HID + ncol] = h;
                }
            }
        }
}

// ---- MFMA bf16 GEMM (mode 0): C[M,N] (+)= A[M,K] @ W[N,K]^T (+bias) ----
__device__ __forceinline__ void gemm_tile(const u16* __restrict__ A, const u16* __restrict__ W,
                                          const float* __restrict__ bias, float* __restrict__ C,
                                          int M, int N, int K, int acc,
                                          u16* Als, u16* Wls) {
    int tid = threadIdx.x;
    int bm = blockIdx.x * 128, bn = blockIdx.y * 128;
    int wave = tid >> 6, lane = tid & 63;
    int wm = (wave & 1) * 64, wn = (wave >> 1) * 64;
    int l15 = lane & 15, quad = lane >> 4;
    f32x4 accf[4][4] = {};
    for (int k0 = 0; k0 < K; k0 += 32) {
#pragma unroll
        for (int h = 0; h < 2; ++h) {
            int ch = tid + h * 256;
            int row = ch >> 2, kc = (ch & 3) * 8;
            int gr = bm + row;
            float4 av = make_float4(0.f, 0.f, 0.f, 0.f);
            if (gr < M) av = *(const float4*)(A + (size_t)gr * K + k0 + kc);
            *(float4*)&Als[row * 40 + kc] = av;
            int wr = bn + row;
            float4 wv_ = *(const float4*)(W + (size_t)wr * K + k0 + kc);
            *(float4*)&Wls[row * 40 + kc] = wv_;
        }
        __syncthreads();
        bf16x8 af[4], bfr[4];
#pragma unroll
        for (int r = 0; r < 4; ++r)
            af[r] = *(const bf16x8*)&Als[(wm + r * 16 + l15) * 40 + quad * 8];
#pragma unroll
        for (int c2 = 0; c2 < 4; ++c2)
            bfr[c2] = *(const bf16x8*)&Wls[(wn + c2 * 16 + l15) * 40 + quad * 8];
#pragma unroll
        for (int r = 0; r < 4; ++r)
#pragma unroll
            for (int c2 = 0; c2 < 4; ++c2)
                accf[r][c2] = __builtin_amdgcn_mfma_f32_16x16x32_bf16(af[r], bfr[c2], accf[r][c2], 0, 0, 0);
        __syncthreads();
    }
#pragma unroll
    for (int r = 0; r < 4; ++r) {
#pragma unroll
        for (int c2 = 0; c2 < 4; ++c2) {
            int ncol = bn + wn + c2 * 16 + l15;
            float bv = bias ? bias[ncol] : 0.f;
#pragma unroll
            for (int reg = 0; reg < 4; ++reg) {
                int mrow = bm + wm + r * 16 + quad * 4 + reg;
                if (mrow >= M) continue;
                float v = accf[r][c2][reg] + bv;
                if (acc) v += C[(size_t)mrow * N + ncol];
                C[(size_t)mrow * N + ncol] = v;
            }
        }
    }
}

__global__ __launch_bounds__(256) void k_gemm_mfma(const u16* __restrict__ A,
                                                   const u16* __restrict__ W,
                                                   const float* __restrict__ bias,
                                                   float* __restrict__ C,
                                                   int M, int N, int K, int acc) {
    __shared__ u16 Als[128 * 40];
    __shared__ u16 Wls[128 * 40];
    gemm_tile(A, W, bias, C, M, N, K, acc, Als, Wls);
}

// ---- QKVSE GEMM: bf16 QB output (all 768 cols) + f32 skip side-copy + sortscat slice ----
__global__ __launch_bounds__(256) void k_gemm_qkvse(const u16* __restrict__ A,
                                                    const u16* __restrict__ W,
                                                    const float* __restrict__ bias,
                                                    u16* __restrict__ QB,
                                                    float* __restrict__ SkipF,
                                                    const int* __restrict__ eidx,
                                                    int* __restrict__ cursor,
                                                    int* __restrict__ sorted) {
    __shared__ u16 Als[128 * 40];
    __shared__ u16 Wls[128 * 40];
    if (blockIdx.y == 6) {
        int j = blockIdx.x * 256 + threadIdx.x;
        for (; j < NEDGE; j += 157 * 256) {
            int d = eidx[NEDGE + j];
            int pos = atomicAdd(&cursor[d], 1);
            sorted[pos] = j;
        }
        return;
    }
    int tid = threadIdx.x;
    int bm = blockIdx.x * 128, bn = blockIdx.y * 128;
    int wave = tid >> 6, lane = tid & 63;
    int wm = (wave & 1) * 64, wn = (wave >> 1) * 64;
    int l15 = lane & 15, quad = lane >> 4;
    f32x4 accf[4][4] = {};
    for (int k0 = 0; k0 < 128; k0 += 32) {
#pragma unroll
        for (int h = 0; h < 2; ++h) {
            int ch = tid + h * 256;
            int row = ch >> 2, kc = (ch & 3) * 8;
            int gr = bm + row;
            float4 av = make_float4(0.f, 0.f, 0.f, 0.f);
            if (gr < NNODE) av = *(const float4*)(A + (size_t)gr * 128 + k0 + kc);
            *(float4*)&Als[row * 40 + kc] = av;
            int wr = bn + row;
            float4 wv_ = *(const float4*)(W + (size_t)wr * 128 + k0 + kc);
            *(float4*)&Wls[row * 40 + kc] = wv_;
        }
        __syncthreads();
        bf16x8 af[4], bfr[4];
#pragma unroll
        for (int r = 0; r < 4; ++r)
            af[r] = *(const bf16x8*)&Als[(wm + r * 16 + l15) * 40 + quad * 8];
#pragma unroll
        for (int c2 = 0; c2 < 4; ++c2)
            bfr[c2] = *(const bf16x8*)&Wls[(wn + c2 * 16 + l15) * 40 + quad * 8];
#pragma unroll
        for (int r = 0; r < 4; ++r)
#pragma unroll
            for (int c2 = 0; c2 < 4; ++c2)
                accf[r][c2] = __builtin_amdgcn_mfma_f32_16x16x32_bf16(af[r], bfr[c2], accf[r][c2], 0, 0, 0);
        __syncthreads();
    }
#pragma unroll
    for (int r = 0; r < 4; ++r) {
#pragma unroll
        for (int c2 = 0; c2 < 4; ++c2) {
            int ncol = bn + wn + c2 * 16 + l15;
            float bv = bias[ncol];
#pragma unroll
            for (int reg = 0; reg < 4; ++reg) {
                int mrow = bm + wm + r * 16 + quad * 4 + reg;
                if (mrow >= NNODE) continue;
                float v = accf[r][c2][reg] + bv;
                QB[(size_t)mrow * 768 + ncol] = f2b(v);
                if (ncol >= 384 && ncol < 512)
                    SkipF[(size_t)mrow * 128 + (ncol - 384)] = v;
            }
        }
    }
}

// ---- node-feature build (blocks 0..2499, 8 rows each) + degree scan (block 2500) ----
__global__ __launch_bounds__(1024) void k_x_scan(const int* __restrict__ node_ids,
                                                 const float* __restrict__ nf,
                                                 const float* __restrict__ memory,
                                                 u16* __restrict__ Xb,
                                                 const int* __restrict__ deg,
                                                 int* __restrict__ offs,
                                                 int* __restrict__ cursor) {
    __shared__ int wsum[16];
    int p = blockIdx.x, t = threadIdx.x;
    if (p < 2500) {
        int row = p * 8 + (t >> 7), c = t & 127;
        int nid = node_ids[row];
        Xb[(size_t)row * HID + c] = f2b(nf[(size_t)nid * HID + c] + memory[(size_t)nid * HID + c]);
        return;
    }
    int lane = t & 63, w = t >> 6;
    int carry = 0;
    const int N4 = NNODE / 4;   // 5000
    for (int base = 0; base < N4; base += 1024) {
        int i4 = base + t;
        int4 v = make_int4(0, 0, 0, 0);
        if (i4 < N4) v = ((const int4*)deg)[i4];
        int s = v.x + v.y + v.z + v.w;
        int x = s;
#pragma unroll
        for (int d = 1; d < 64; d <<= 1) { int y = __shfl_up(x, d, 64); if (lane >= d) x += y; }
        if (lane == 63) wsum[w] = x;
        __syncthreads();
        int add = 0, tot = 0;
        for (int k2 = 0; k2 < 16; ++k2) { int ss = wsum[k2]; if (k2 < w) add += ss; tot += ss; }
        if (i4 < N4) {
            int e = carry + add + x - s;
            int4 o;
            o.x = e;
            o.y = e + v.x;
            o.z = o.y + v.y;
            o.w = o.z + v.z;
            ((int4*)offs)[i4] = o;
            ((int4*)cursor)[i4] = o;
        }
        carry += tot;
        __syncthreads();
    }
    if (t == 0) offs[NNODE] = NEDGE;
}

// ---- fused per-node attention: 4-edge batched online softmax ----
__global__ __launch_bounds__(256) void k_node(const u16* __restrict__ QB,
        const float* __restrict__ SkipF, const int* __restrict__ offs,
        const int* __restrict__ sorted, const int* __restrict__ eidx,
        const int* __restrict__ edge_ids, const float* __restrict__ last_update,
        const float* __restrict__ time_w, const float* __restrict__ time_b,
        const float* __restrict__ ef, const int* __restrict__ tptr,
        float* __restrict__ out, u16* __restrict__ saccb) {
    int wave = threadIdx.x >> 6, lane = threadIdx.x & 63;
    int n = blockIdx.x * 4 + wave;
    int c = 2 * lane;
    const u16* rowq = QB + (size_t)n * 768;
    unsigned qw  = *(const unsigned*)(rowq + c);
    unsigned qtw = *(const unsigned*)(rowq + 512 + c);
    unsigned qfw = *(const unsigned*)(rowq + 640 + c);
    float2 qd, qet, qef;
    qd.x  = b2f(qw & 0xffffu);  qd.y  = b2f(qw >> 16);
    qet.x = b2f(qtw & 0xffffu); qet.y = b2f(qtw >> 16);
    qef.x = b2f(qfw & 0xffffu); qef.y = b2f(qfw >> 16);
    float2 skip = *(const float2*)(SkipF + (size_t)n * HID + c);
    float2 tw   = *(const float2*)(time_w + c);
    float2 tb   = *(const float2*)(time_b + c);
    float tf = (float)(*tptr);
    int start = offs[n], end = offs[n + 1];
    int deg = end - start;
    if (deg == 0) {
        *(float2*)(out + (size_t)n * HID + c) = skip;
        *(unsigned*)(saccb + (size_t)n * 256 + c) = 0u;
        *(unsigned*)(saccb + (size_t)n * 256 + 128 + c) = 0u;
        return;
    }
    float m = -1e30f, l_ = 0.f;
    float va0 = 0.f, va1 = 0.f, s00 = 0.f, s01 = 0.f, s10 = 0.f, s11 = 0.f;
    for (int cb = start; cb < end; cb += 64) {
        int cnt = end - cb; if (cnt > 64) cnt = 64;
        int s_l = 0, eid_l = 0; float rt_l = 0.f;
        if (lane < cnt) {
            int j = sorted[cb + lane];
            s_l = eidx[j];
            eid_l = edge_ids[j];
            rt_l = tf - last_update[eid_l];
        }
        for (int e0 = 0; e0 < cnt; e0 += 4) {
            float pv[4], cv0[4], cv1[4], vx[4], vy[4], ex[4], ey[4];
#pragma unroll
            for (int i = 0; i < 4; ++i) {
                int idx = e0 + i;
                int sel = (idx < cnt) ? idx : e0;
                int s   = __shfl(s_l, sel, 64);
                int eid = __shfl(eid_l, sel, 64);
                float rt = __shfl(rt_l, sel, 64);
                unsigned kvp = *(const unsigned*)(QB + (size_t)s * 768 + 128 + c);
                unsigned vvp = *(const unsigned*)(QB + (size_t)s * 768 + 256 + c);
                float2 ev = *(const float2*)(ef + (size_t)eid * HID + c);
                float k0f = b2f(kvp & 0xffffu), k1f = b2f(kvp >> 16);
                vx[i] = b2f(vvp & 0xffffu); vy[i] = b2f(vvp >> 16);
                cv0[i] = __cosf(rt * tw.x + tb.x);
                cv1[i] = __cosf(rt * tw.y + tb.y);
                ex[i] = ev.x; ey[i] = ev.y;
                pv[i] = qd.x * k0f + qd.y * k1f + qet.x * cv0[i] + qet.y * cv1[i]
                      + qef.x * ev.x + qef.y * ev.y;
            }
#pragma unroll
            for (int msk = 32; msk > 0; msk >>= 1) {
#pragma unroll
                for (int i = 0; i < 4; ++i) pv[i] += __shfl_xor(pv[i], msk, 64);
            }
            float al[4];
#pragma unroll
            for (int i = 0; i < 4; ++i)
                al[i] = (e0 + i < cnt) ? pv[i] * 0.08838834764831845f : -1e30f;
            float gm = fmaxf(fmaxf(al[0], al[1]), fmaxf(al[2], al[3]));
            if (gm > m) {
                float fac = __expf(m - gm);
                l_ *= fac; va0 *= fac; va1 *= fac;
                s00 *= fac; s01 *= fac; s10 *= fac; s11 *= fac;
                m = gm;
            }
#pragma unroll
            for (int i = 0; i < 4; ++i) {
                float w = __expf(al[i] - m);
                l_ += w;
                va0 += w * vx[i]; va1 += w * vy[i];
                s00 += w * cv0[i]; s01 += w * cv1[i];
                s10 += w * ex[i]; s11 += w * ey[i];
            }
        }
    }
    float inv = 1.f / fmaxf(l_, 1e-16f);
    float2 o; o.x = va0 * inv + skip.x; o.y = va1 * inv + skip.y;
    *(float2*)(out + (size_t)n * HID + c) = o;
    unsigned p0 = (unsigned)f2b(s00 * inv) | ((unsigned)f2b(s01 * inv) << 16);
    unsigned p1 = (unsigned)f2b(s10 * inv) | ((unsigned)f2b(s11 * inv) << 16);
    *(unsigned*)(saccb + (size_t)n * 256 + c) = p0;
    *(unsigned*)(saccb + (size_t)n * 256 + 128 + c) = p1;
}

extern "C" void kernel_launch(void* const* d_in, const int* in_sizes, int n_in,
                              void* d_out, int out_size, void* d_ws, size_t ws_size,
                              hipStream_t stream) {
    const int*   et_ids        = (const int*)d_in[0];
    const int*   src_ids       = (const int*)d_in[1];
    const float* src_mask      = (const float*)d_in[2];
    const int*   dst_ids       = (const int*)d_in[3];
    const float* dst_mask      = (const float*)d_in[4];
    const int*   ev_eids       = (const int*)d_in[5];
    const float* ev_emb        = (const float*)d_in[6];
    const float* ev_mask       = (const float*)d_in[7];
    const float* ev_ts         = (const float*)d_in[8];
    const int*   node_ids      = (const int*)d_in[9];
    const int*   edge_ids      = (const int*)d_in[10];
    const int*   edge_index    = (const int*)d_in[11];
    const int*   tptr          = (const int*)d_in[12];
    float*       memory        = (float*)d_in[13];
    const float* last_update   = (const float*)d_in[14];
    const float* node_features = (const float*)d_in[15];
    const float* edge_features = (const float*)d_in[16];
    const float* time_w        = (const float*)d_in[17];
    const float* time_b        = (const float*)d_in[18];
    const float* w_ih          = (const float*)d_in[19];
    const float* w_hh          = (const float*)d_in[20];
    const float* b_ih          = (const float*)d_in[21];
    const float* b_hh          = (const float*)d_in[22];
    const float* wq            = (const float*)d_in[23];
    const float* bq            = (const float*)d_in[24];
    const float* wk            = (const float*)d_in[25];
    const float* bk            = (const float*)d_in[26];
    const float* wv            = (const float*)d_in[27];
    const float* bv            = (const float*)d_in[28];
    const float* we            = (const float*)d_in[29];
    const float* wskip         = (const float*)d_in[30];
    const float* bskip         = (const float*)d_in[31];
    float* out = (float*)d_out;
    char*  wsb = (char*)d_ws;

    u16*   Wcatb    = (u16*)(wsb + OFF_WCATB);
    u16*   we_b     = (u16*)(wsb + OFF_WEB);
    u16*   Wallb    = (u16*)(wsb + OFF_WALLB);
    float* ball     = (float*)(wsb + OFF_BALL);
    int*   head_src = (int*)(wsb + OFF_HEAD_SRC);
    int*   head_dst = (int*)(wsb + OFF_HEAD_DST);
    int*   cnt_src  = (int*)(wsb + OFF_CNT_SRC);
    int*   cnt_dst  = (int*)(wsb + OFF_CNT_DST);
    int*   chain_src= (int*)(wsb + OFF_CHAIN_SRC);
    int*   chain_dst= (int*)(wsb + OFF_CHAIN_DST);
    u16*   XHb      = (u16*)(wsb + OFF_XHB);
    float* Hg       = (float*)(wsb + OFF_HG);
    u16*   Xb       = (u16*)(wsb + OFF_XB);
    u16*   QB       = (u16*)(wsb + OFF_QB);
    float* SkipF    = (float*)(wsb + OFF_SKIPF);
    int*   deg      = (int*)(wsb + OFF_DEG);
    int*   offs     = (int*)(wsb + OFF_OFFS);
    int*   cursor   = (int*)(wsb + OFF_CURSOR);
    int*   sorted   = (int*)(wsb + OFF_SORTED);
    u16*   saccb    = (u16*)(wsb + OFF_SACCB);

    // 1: weight prep + deg zero + table clears
    k_prep<<<2000, 256, 0, stream>>>(w_ih, w_hh, we, wq, wk, wv, wskip, bq, bk, bv, bskip,
                                     Wcatb, we_b, Wallb, ball, deg, wsb + OFF_HEAD_SRC);
    // 2: messages + tables/chains + deg hist
    k_msg_tables<<<6628, 128, 0, stream>>>(et_ids, src_ids, src_mask, dst_ids, dst_mask, ev_eids,
                                           ev_emb, ev_mask, ev_ts, memory, last_update, time_w, time_b,
                                           head_src, head_dst, cnt_src, cnt_dst, chain_src, chain_dst,
                                           edge_index, deg, XHb, Hg);
    // 3: dup-group mean fixup
    k_fix<<<2 * EVT, 128, 0, stream>>>(src_ids, dst_ids, head_src, head_dst, chain_src, chain_dst,
                                       cnt_src, cnt_dst, et_ids, src_mask, dst_mask, ev_eids,
                                       ev_emb, ev_mask, ev_ts, memory, last_update, time_w, time_b,
                                       XHb);
    // 4: fused gates GEMM + GRU + memory scatter
    k_gates<<<64, 256, 0, stream>>>(XHb, Wcatb, b_ih, b_hh, Hg, src_ids, dst_ids, cnt_dst, memory);
    // 5: node features + degree scan
    k_x_scan<<<2501, 1024, 0, stream>>>(node_ids, node_features, memory, Xb, deg, offs, cursor);
    // 6: QKVSE GEMM (bf16 QB + f32 skip) + sortscat slice
    k_gemm_qkvse<<<dim3(157, 7), 256, 0, stream>>>(Xb, Wallb, ball, QB, SkipF,
                                                   edge_index, cursor, sorted);
    // 7: per-node attention
    k_node<<<NNODE / 4, 256, 0, stream>>>(QB, SkipF, offs, sorted, edge_index, edge_ids,
                                          last_update, time_w, time_b, edge_features, tptr,
                                          out, saccb);
    // 8: final edge-feature GEMM (accumulate into out)
    k_gemm_mfma<<<dim3(157, 1), 256, 0, stream>>>(saccb, we_b, nullptr, out, NNODE, 128, 256, 1);
}

// Round 5
// 480.843 us; speedup vs baseline: 1.1192x; 1.1192x over previous
//
#include <hip/hip_runtime.h>
#include <math.h>

#define HID   128
#define MAXN  100000
#define MAXE  300000
#define EVT   4096
#define NNODE 20000
#define NEDGE 320000

typedef unsigned short u16;
typedef __attribute__((ext_vector_type(8))) short bf16x8;
typedef __attribute__((ext_vector_type(4))) float f32x4;

// ---------------- workspace layout (bytes) ----------------
// PERSIST (weights)
#define OFF_WCATB     0u                    // 384*768 bf16 = 589824  ([w_ih | w_hh] concat)
#define OFF_WEB       589824u               // 128*256 bf16 = 65536
#define OFF_WALLB     655360u               // 768*128 bf16 = 196608
#define OFF_BALL      851968u               // 768 f32 = 3072
#define BASE2         855040u
// EVENT arena
#define OFF_HEAD_SRC  (BASE2 + 0u)          // MAXN i32 (0xFF init)
#define OFF_HEAD_DST  (BASE2 + 400128u)     // MAXN i32 (0xFF init)
#define OFF_CNT_SRC   (BASE2 + 800256u)     // MAXN i32 (0 init)
#define OFF_CNT_DST   (BASE2 + 1200384u)    // MAXN i32 (0 init)
#define OFF_CHAIN_SRC (BASE2 + 1600512u)    // EVT i32
#define OFF_CHAIN_DST (BASE2 + 1616896u)    // EVT i32
#define OFF_XHB       (BASE2 + 1703936u)    // 8192*768 bf16 = 12582912 (msg cols 0..640 | mem-bf16 cols 640..768)
#define OFF_HG        (BASE2 + 14286848u)   // 8192*128 f32 = 4194304 (f32 pre-update memory rows)
// GATE buffers (dead after k_gru_scatter; alias NODE arena written later)
#define OFF_GRZ       (BASE2 + 20000000u)   // 8192*256 f32 = 8388608 (r,z pre-activations, summed)
#define OFF_GIN       (BASE2 + 28388608u)   // 8192*128 f32 = 4194304 (gi_n + b_ih_n)
#define OFF_GHN       (BASE2 + 32582912u)   // 8192*128 f32 = 4194304 (gh_n + b_hh_n)
// NODE arena (XB/QB written AFTER gate buffers are dead -- stream-ordered, safe)
#define OFF_XB        (BASE2 + 20000000u)   // 20000*128 bf16 = 5120000
#define OFF_QB        (BASE2 + 25120000u)   // 20000*768 bf16 = 30720000
#define OFF_SKIPF     (BASE2 + 55840000u)   // 20000*128 f32 = 10240000
#define OFF_DEG       (BASE2 + 66080000u)   // 20000 i32
#define OFF_OFFS      (BASE2 + 66160128u)   // 20001 i32
#define OFF_CURSOR    (BASE2 + 66240256u)   // 20000 i32
#define OFF_SORTED    (BASE2 + 66320384u)   // 320000 i32
#define OFF_SACCB     (BASE2 + 67600384u)   // 20000*256 bf16 = 10240000
// peak ~78.5 MB

__device__ __forceinline__ float sigmoidf_(float x) { return 1.f / (1.f + __expf(-x)); }
__device__ __forceinline__ u16 f2b(float f) {
    unsigned u = __float_as_uint(f);
    unsigned r = (u + 0x7fffu + ((u >> 16) & 1u)) >> 16;
    return (u16)r;
}
__device__ __forceinline__ float b2f(unsigned h) { return __uint_as_float(h << 16); }

// ---- fused weight prep: Wcat build + we convert + Wall build + deg zero + table clears ----
__global__ void k_prep(const float* __restrict__ w_ih, const float* __restrict__ w_hh,
                       const float* __restrict__ we,
                       const float* __restrict__ wq, const float* __restrict__ wk_,
                       const float* __restrict__ wv, const float* __restrict__ wskip,
                       const float* __restrict__ bq, const float* __restrict__ bk,
                       const float* __restrict__ bv, const float* __restrict__ bskip,
                       u16* __restrict__ Wcatb, u16* __restrict__ we_b,
                       u16* __restrict__ Wallb, float* __restrict__ ball,
                       int* __restrict__ deg, char* __restrict__ zbase) {
    int b = blockIdx.x, t = threadIdx.x;
    if (b < 1152) {                     // Wcat: 384 rows x 768 cols
        int idx = b * 256 + t;
        int row = idx / 768, col = idx % 768;
        float v = (col < 640) ? w_ih[row * 640 + col] : w_hh[row * 128 + (col - 640)];
        Wcatb[idx] = f2b(v);
        return;
    }
    b -= 1152;
    if (b < 128) {                      // we: 128*256
        int i = b * 256 + t;
        we_b[i] = f2b(we[i]);
        return;
    }
    b -= 128;
    if (b < 79) {                       // deg zero
        int i = b * 256 + t;
        if (i < NNODE) deg[i] = 0;
        return;
    }
    b -= 79;
    if (b < 384) {                      // Wall build: 768*128
        int idx = b * 256 + t;
        int row = idx >> 7;
        int k = idx & 127;
        float v;
        if (row < 128)      v = wq[row * 128 + k];
        else if (row < 256) v = wk_[(row - 128) * 128 + k];
        else if (row < 384) v = wv[(row - 256) * 128 + k];
        else if (row < 512) v = wskip[(row - 384) * 128 + k];
        else {
            int j = row - 512;
            float a = 0.f;
            for (int t2 = 0; t2 < 128; t2++) a += wq[t2 * 128 + k] * we[t2 * 256 + j];
            v = a;
        }
        Wallb[row * 128 + k] = f2b(v);
        if (k == 0) {
            float bb;
            if (row < 128)      bb = bq[row];
            else if (row < 256) bb = bk[row - 128];
            else if (row < 384) bb = bv[row - 256];
            else if (row < 512) bb = bskip[row - 384];
            else { int j = row - 512; float a = 0.f; for (int t2 = 0; t2 < 128; t2++) a += bq[t2] * we[t2 * 256 + j]; bb = a; }
            ball[row] = bb;
        }
        return;
    }
    b -= 384;
    // table clears: heads (0xFF, 800256 B) then cnts (0, 800256 B), 16B chunks
    const int NFF = 50016;     // 800256/16
    uint4 ff = make_uint4(0xFFFFFFFFu, 0xFFFFFFFFu, 0xFFFFFFFFu, 0xFFFFFFFFu);
    uint4 zz = make_uint4(0u, 0u, 0u, 0u);
    int idx = b * 256 + t;
    int stride = 257 * 256;
    uint4* pff = (uint4*)zbase;
    uint4* pzz = (uint4*)(zbase + 800256);
    for (int i = idx; i < NFF; i += stride) pff[i] = ff;
    for (int i = idx; i < NFF; i += stride) pzz[i] = zz;
}

// ---- fused: messages (direct XHb/Hg write) + id tables/chains + dst-deg hist ----
__global__ void k_msg_tables(const int* __restrict__ et_ids, const int* __restrict__ src_ids,
                          const float* __restrict__ src_mask, const int* __restrict__ dst_ids,
                          const float* __restrict__ dst_mask, const int* __restrict__ ev_eids,
                          const float* __restrict__ ev_emb, const float* __restrict__ ev_mask,
                          const float* __restrict__ ev_ts, const float* __restrict__ memory,
                          const float* __restrict__ last_update, const float* __restrict__ time_w,
                          const float* __restrict__ time_b,
                          int* __restrict__ head_src, int* __restrict__ head_dst,
                          int* __restrict__ cnt_src, int* __restrict__ cnt_dst,
                          int* __restrict__ chain_src, int* __restrict__ chain_dst,
                          const int* __restrict__ eidx, int* __restrict__ deg,
                          u16* __restrict__ XHb, float* __restrict__ Hg) {
    int b = blockIdx.x, t = threadIdx.x;
    if (b >= EVT) {
        int bb = b - EVT;
        if (bb < 32) {                       // tables: 4096 events
            int i = bb * 128 + t;
            int s = src_ids[i], d = dst_ids[i];
            chain_src[i] = atomicExch(&head_src[s], i);
            atomicAdd(&cnt_src[s], 1);
            chain_dst[i] = atomicExch(&head_dst[d], i);
            atomicAdd(&cnt_dst[d], 1);
        } else {                             // deg hist: 320000 edges
            int j = (bb - 32) * 128 + t;
            atomicAdd(&deg[eidx[NEDGE + j]], 1);
        }
        return;
    }
    int i = b;
    int c = t;
    int et = et_ids[i];
    float sm = src_mask[i], dm = dst_mask[i], em = ev_mask[i], ts = ev_ts[i];
    int sid = src_ids[i], did = dst_ids[i], eid = ev_eids[i];
    float isnode = (et == 3 || et == 4) ? 1.f : 0.f;
    float rel = ts - last_update[eid] * dm;
    float tval = ts * isnode + rel * dm;
    float tse = __cosf(tval * time_w[c] + time_b[c]) * em;
    float typ = (float)et;
    float sv_raw = memory[(size_t)sid * HID + c];
    float dv_raw = memory[(size_t)did * HID + c];
    float sv = sv_raw * sm;
    float dv = dv_raw * dm;
    float ev = ev_emb[(size_t)i * HID + c];
    Hg[(size_t)i * HID + c] = sv_raw;
    Hg[(size_t)(EVT + i) * HID + c] = dv_raw;
    u16* xs = XHb + (size_t)i * 768;
    xs[c] = f2b(typ * em); xs[128 + c] = f2b(sv * em); xs[256 + c] = f2b(dv * em);
    xs[384 + c] = f2b(tse * em); xs[512 + c] = f2b(ev * em);
    xs[640 + c] = f2b(sv_raw);
    u16* xd = XHb + (size_t)(EVT + i) * 768;
    xd[c] = f2b(typ * dm); xd[128 + c] = f2b(dv * dm); xd[256 + c] = f2b(sv * dm);
    xd[384 + c] = f2b(tse * dm); xd[512 + c] = f2b(ev * dm);
    xd[640 + c] = f2b(dv_raw);
}

// ---- fixup: rows whose id has cnt>1 recompute the group mean via chain walk ----
__global__ void k_fix(const int* __restrict__ src_ids, const int* __restrict__ dst_ids,
                      const int* __restrict__ head_src, const int* __restrict__ head_dst,
                      const int* __restrict__ chain_src, const int* __restrict__ chain_dst,
                      const int* __restrict__ cnt_src, const int* __restrict__ cnt_dst,
                      const int* __restrict__ et_ids, const float* __restrict__ src_mask,
                      const float* __restrict__ dst_mask, const int* __restrict__ ev_eids,
                      const float* __restrict__ ev_emb, const float* __restrict__ ev_mask,
                      const float* __restrict__ ev_ts, const float* __restrict__ memory,
                      const float* __restrict__ last_update, const float* __restrict__ time_w,
                      const float* __restrict__ time_b, u16* __restrict__ XHb) {
    int r = blockIdx.x, c = threadIdx.x;
    bool is_src = (r < EVT);
    int id = is_src ? src_ids[r] : dst_ids[r - EVT];
    int cnt = is_src ? cnt_src[id] : cnt_dst[id];
    if (cnt < 2) return;
    float own = memory[(size_t)id * HID + c];
    float tw = time_w[c], tb = time_b[c];
    float a0 = 0.f, a1 = 0.f, a2 = 0.f, a3 = 0.f, a4 = 0.f;
    int j = is_src ? head_src[id] : head_dst[id];
    for (int k = 0; k < cnt; ++k) {
        int et = et_ids[j];
        float sm = src_mask[j], dm = dst_mask[j], em = ev_mask[j], ts = ev_ts[j];
        int eid = ev_eids[j];
        float isnode = (et == 3 || et == 4) ? 1.f : 0.f;
        float rel = ts - last_update[eid] * dm;
        float tval = ts * isnode + rel * dm;
        float tse = __cosf(tval * tw + tb);
        float ev = ev_emb[(size_t)j * HID + c];
        float typ = (float)et;
        if (is_src) {
            float sv = own * sm;
            float dv = memory[(size_t)dst_ids[j] * HID + c] * dm;
            float tsm = tse * em;
            a0 += typ * em; a1 += sv * em; a2 += dv * em;
            a3 += tsm * em; a4 += ev * em;
            j = chain_src[j];
        } else {
            float dv = own * dm;
            float sv = memory[(size_t)src_ids[j] * HID + c] * sm;
            float tsm = tse * em;
            a0 += typ * dm; a1 += dv * dm; a2 += sv * dm;
            a3 += tsm * dm; a4 += ev * dm;
            j = chain_dst[j];
        }
    }
    float inv = 1.f / (float)cnt;
    u16* x = XHb + (size_t)r * 768;
    x[c] = f2b(a0 * inv); x[128 + c] = f2b(a1 * inv); x[256 + c] = f2b(a2 * inv);
    x[384 + c] = f2b(a3 * inv); x[512 + c] = f2b(a4 * inv);
}

// ---- shared MFMA K-pass: acc += A[128 strip, K] @ W[128 rows, K]^T (strided) ----
__device__ __forceinline__ void gate_pass(const u16* __restrict__ A, int lda,
                                          const u16* __restrict__ W, int ldw, int K,
                                          f32x4 acc[4][4], u16* Als, u16* Wls,
                                          int bm, int wm, int wn, int l15, int quad, int tid) {
    for (int k0 = 0; k0 < K; k0 += 32) {
#pragma unroll
        for (int h = 0; h < 2; ++h) {
            int ch = tid + h * 256;
            int row = ch >> 2, kc = (ch & 3) * 8;
            *(float4*)&Als[row * 40 + kc] = *(const float4*)(A + (size_t)(bm + row) * lda + k0 + kc);
            *(float4*)&Wls[row * 40 + kc] = *(const float4*)(W + (size_t)row * ldw + k0 + kc);
        }
        __syncthreads();
        bf16x8 af[4], bfr[4];
#pragma unroll
        for (int r = 0; r < 4; ++r)
            af[r] = *(const bf16x8*)&Als[(wm + r * 16 + l15) * 40 + quad * 8];
#pragma unroll
        for (int c2 = 0; c2 < 4; ++c2)
            bfr[c2] = *(const bf16x8*)&Wls[(wn + c2 * 16 + l15) * 40 + quad * 8];
#pragma unroll
        for (int r = 0; r < 4; ++r)
#pragma unroll
            for (int c2 = 0; c2 < 4; ++c2)
                acc[r][c2] = __builtin_amdgcn_mfma_f32_16x16x32_bf16(af[r], bfr[c2], acc[r][c2], 0, 0, 0);
        __syncthreads();
    }
}

// ---- gates GEMM: grid (64 m-strips, 3 gates); each block computes gi (K=640) AND gh (K=128)
// for its (m,gate) tile. g<2: write Grz = gi+gh+biases. g==2: write gi_n, gh_n separately. ----
__global__ __launch_bounds__(256) void k_gemm_gates(const u16* __restrict__ XHb,
        const u16* __restrict__ Wcat, const float* __restrict__ b_ih,
        const float* __restrict__ b_hh, float* __restrict__ Grz,
        float* __restrict__ Gin, float* __restrict__ Ghn) {
    __shared__ u16 Als[128 * 40];
    __shared__ u16 Wls[128 * 40];
    int tid = threadIdx.x;
    int bm = blockIdx.x * 128;
    int g = blockIdx.y;
    int wave = tid >> 6, lane = tid & 63;
    int wm = (wave & 1) * 64, wn = (wave >> 1) * 64;
    int l15 = lane & 15, quad = lane >> 4;
    f32x4 acc_i[4][4] = {};
    f32x4 acc_h[4][4] = {};
    const u16* Wg = Wcat + (size_t)(g * 128) * 768;
    // gi: X (cols 0..640) @ W_ih_g^T, K=640
    gate_pass(XHb, 768, Wg, 768, 640, acc_i, Als, Wls, bm, wm, wn, l15, quad, tid);
    // gh: H (cols 640..768) @ W_hh_g^T, K=128
    gate_pass(XHb + 640, 768, Wg + 640, 768, 128, acc_h, Als, Wls, bm, wm, wn, l15, quad, tid);
#pragma unroll
    for (int r = 0; r < 4; ++r) {
#pragma unroll
        for (int c2 = 0; c2 < 4; ++c2) {
            int ncol = wn + c2 * 16 + l15;
            float bi = b_ih[g * 128 + ncol];
            float bh = b_hh[g * 128 + ncol];
#pragma unroll
            for (int reg = 0; reg < 4; ++reg) {
                int mrow = bm + wm + r * 16 + quad * 4 + reg;
                if (g < 2) {
                    Grz[(size_t)mrow * 256 + g * 128 + ncol] =
                        acc_i[r][c2][reg] + acc_h[r][c2][reg] + bi + bh;
                } else {
                    Gin[(size_t)mrow * 128 + ncol] = acc_i[r][c2][reg] + bi;
                    Ghn[(size_t)mrow * 128 + ncol] = acc_h[r][c2][reg] + bh;
                }
            }
        }
    }
}

// ---- GRU gate combine + scatter-to-memory (dst overrides src) ----
// Reference: memory[src_ids]=new_src then memory[dst_ids]=new_dst. A src-row
// write is visible only if its id never appears as a dst id (cnt_dst==0).
__global__ void k_gru_scatter(const float* __restrict__ Grz, const float* __restrict__ Gin,
                              const float* __restrict__ Ghn, const float* __restrict__ Hg,
                              const int* __restrict__ src_ids, const int* __restrict__ dst_ids,
                              const int* __restrict__ cnt_dst, float* __restrict__ memory) {
    int r = blockIdx.x, c = threadIdx.x;
    float rg = sigmoidf_(Grz[(size_t)r * 256 + c]);
    float z  = sigmoidf_(Grz[(size_t)r * 256 + 128 + c]);
    float n  = tanhf(Gin[(size_t)r * 128 + c] + rg * Ghn[(size_t)r * 128 + c]);
    float h0 = Hg[(size_t)r * HID + c];
    float h  = (1.f - z) * n + z * h0;
    if (r < EVT) {
        int sid = src_ids[r];
        if (cnt_dst[sid] == 0) memory[(size_t)sid * HID + c] = h;
    } else {
        int did = dst_ids[r - EVT];
        memory[(size_t)did * HID + c] = h;
    }
}

// ---- MFMA bf16 GEMM (generic): C[M,N] (+)= A[M,K] @ W[N,K]^T (+bias) ----
__device__ __forceinline__ void gemm_tile(const u16* __restrict__ A, const u16* __restrict__ W,
                                          const float* __restrict__ bias, float* __restrict__ C,
                                          int M, int N, int K, int acc,
                                          u16* Als, u16* Wls) {
    int tid = threadIdx.x;
    int bm = blockIdx.x * 128, bn = blockIdx.y * 128;
    int wave = tid >> 6, lane = tid & 63;
    int wm = (wave & 1) * 64, wn = (wave >> 1) * 64;
    int l15 = lane & 15, quad = lane >> 4;
    f32x4 accf[4][4] = {};
    for (int k0 = 0; k0 < K; k0 += 32) {
#pragma unroll
        for (int h = 0; h < 2; ++h) {
            int ch = tid + h * 256;
            int row = ch >> 2, kc = (ch & 3) * 8;
            int gr = bm + row;
            float4 av = make_float4(0.f, 0.f, 0.f, 0.f);
            if (gr < M) av = *(const float4*)(A + (size_t)gr * K + k0 + kc);
            *(float4*)&Als[row * 40 + kc] = av;
            int wr = bn + row;
            float4 wv_ = *(const float4*)(W + (size_t)wr * K + k0 + kc);
            *(float4*)&Wls[row * 40 + kc] = wv_;
        }
        __syncthreads();
        bf16x8 af[4], bfr[4];
#pragma unroll
        for (int r = 0; r < 4; ++r)
            af[r] = *(const bf16x8*)&Als[(wm + r * 16 + l15) * 40 + quad * 8];
#pragma unroll
        for (int c2 = 0; c2 < 4; ++c2)
            bfr[c2] = *(const bf16x8*)&Wls[(wn + c2 * 16 + l15) * 40 + quad * 8];
#pragma unroll
        for (int r = 0; r < 4; ++r)
#pragma unroll
            for (int c2 = 0; c2 < 4; ++c2)
                accf[r][c2] = __builtin_amdgcn_mfma_f32_16x16x32_bf16(af[r], bfr[c2], accf[r][c2], 0, 0, 0);
        __syncthreads();
    }
#pragma unroll
    for (int r = 0; r < 4; ++r) {
#pragma unroll
        for (int c2 = 0; c2 < 4; ++c2) {
            int ncol = bn + wn + c2 * 16 + l15;
            float bv = bias ? bias[ncol] : 0.f;
#pragma unroll
            for (int reg = 0; reg < 4; ++reg) {
                int mrow = bm + wm + r * 16 + quad * 4 + reg;
                if (mrow >= M) continue;
                float v = accf[r][c2][reg] + bv;
                if (acc) v += C[(size_t)mrow * N + ncol];
                C[(size_t)mrow * N + ncol] = v;
            }
        }
    }
}

__global__ __launch_bounds__(256) void k_gemm_mfma(const u16* __restrict__ A,
                                                   const u16* __restrict__ W,
                                                   const float* __restrict__ bias,
                                                   float* __restrict__ C,
                                                   int M, int N, int K, int acc) {
    __shared__ u16 Als[128 * 40];
    __shared__ u16 Wls[128 * 40];
    gemm_tile(A, W, bias, C, M, N, K, acc, Als, Wls);
}

// ---- QKVSE GEMM: bf16 QB output (all 768 cols) + f32 skip side-copy + sortscat slice ----
__global__ __launch_bounds__(256) void k_gemm_qkvse(const u16* __restrict__ A,
                                                    const u16* __restrict__ W,
                                                    const float* __restrict__ bias,
                                                    u16* __restrict__ QB,
                                                    float* __restrict__ SkipF,
                                                    const int* __restrict__ eidx,
                                                    int* __restrict__ cursor,
                                                    int* __restrict__ sorted) {
    __shared__ u16 Als[128 * 40];
    __shared__ u16 Wls[128 * 40];
    if (blockIdx.y == 6) {
        int j = blockIdx.x * 256 + threadIdx.x;
        for (; j < NEDGE; j += 157 * 256) {
            int d = eidx[NEDGE + j];
            int pos = atomicAdd(&cursor[d], 1);
            sorted[pos] = j;
        }
        return;
    }
    int tid = threadIdx.x;
    int bm = blockIdx.x * 128, bn = blockIdx.y * 128;
    int wave = tid >> 6, lane = tid & 63;
    int wm = (wave & 1) * 64, wn = (wave >> 1) * 64;
    int l15 = lane & 15, quad = lane >> 4;
    f32x4 accf[4][4] = {};
    for (int k0 = 0; k0 < 128; k0 += 32) {
#pragma unroll
        for (int h = 0; h < 2; ++h) {
            int ch = tid + h * 256;
            int row = ch >> 2, kc = (ch & 3) * 8;
            int gr = bm + row;
            float4 av = make_float4(0.f, 0.f, 0.f, 0.f);
            if (gr < NNODE) av = *(const float4*)(A + (size_t)gr * 128 + k0 + kc);
            *(float4*)&Als[row * 40 + kc] = av;
            int wr = bn + row;
            float4 wv_ = *(const float4*)(W + (size_t)wr * 128 + k0 + kc);
            *(float4*)&Wls[row * 40 + kc] = wv_;
        }
        __syncthreads();
        bf16x8 af[4], bfr[4];
#pragma unroll
        for (int r = 0; r < 4; ++r)
            af[r] = *(const bf16x8*)&Als[(wm + r * 16 + l15) * 40 + quad * 8];
#pragma unroll
        for (int c2 = 0; c2 < 4; ++c2)
            bfr[c2] = *(const bf16x8*)&Wls[(wn + c2 * 16 + l15) * 40 + quad * 8];
#pragma unroll
        for (int r = 0; r < 4; ++r)
#pragma unroll
            for (int c2 = 0; c2 < 4; ++c2)
                accf[r][c2] = __builtin_amdgcn_mfma_f32_16x16x32_bf16(af[r], bfr[c2], accf[r][c2], 0, 0, 0);
        __syncthreads();
    }
#pragma unroll
    for (int r = 0; r < 4; ++r) {
#pragma unroll
        for (int c2 = 0; c2 < 4; ++c2) {
            int ncol = bn + wn + c2 * 16 + l15;
            float bv = bias[ncol];
#pragma unroll
            for (int reg = 0; reg < 4; ++reg) {
                int mrow = bm + wm + r * 16 + quad * 4 + reg;
                if (mrow >= NNODE) continue;
                float v = accf[r][c2][reg] + bv;
                QB[(size_t)mrow * 768 + ncol] = f2b(v);
                if (ncol >= 384 && ncol < 512)
                    SkipF[(size_t)mrow * 128 + (ncol - 384)] = v;
            }
        }
    }
}

// ---- node-feature build (blocks 0..2499, 8 rows each) + degree scan (block 2500) ----
__global__ __launch_bounds__(1024) void k_x_scan(const int* __restrict__ node_ids,
                                                 const float* __restrict__ nf,
                                                 const float* __restrict__ memory,
                                                 u16* __restrict__ Xb,
                                                 const int* __restrict__ deg,
                                                 int* __restrict__ offs,
                                                 int* __restrict__ cursor) {
    __shared__ int wsum[16];
    int p = blockIdx.x, t = threadIdx.x;
    if (p < 2500) {
        int row = p * 8 + (t >> 7), c = t & 127;
        int nid = node_ids[row];
        Xb[(size_t)row * HID + c] = f2b(nf[(size_t)nid * HID + c] + memory[(size_t)nid * HID + c]);
        return;
    }
    int lane = t & 63, w = t >> 6;
    int carry = 0;
    const int N4 = NNODE / 4;   // 5000
    for (int base = 0; base < N4; base += 1024) {
        int i4 = base + t;
        int4 v = make_int4(0, 0, 0, 0);
        if (i4 < N4) v = ((const int4*)deg)[i4];
        int s = v.x + v.y + v.z + v.w;
        int x = s;
#pragma unroll
        for (int d = 1; d < 64; d <<= 1) { int y = __shfl_up(x, d, 64); if (lane >= d) x += y; }
        if (lane == 63) wsum[w] = x;
        __syncthreads();
        int add = 0, tot = 0;
        for (int k2 = 0; k2 < 16; ++k2) { int ss = wsum[k2]; if (k2 < w) add += ss; tot += ss; }
        if (i4 < N4) {
            int e = carry + add + x - s;
            int4 o;
            o.x = e;
            o.y = e + v.x;
            o.z = o.y + v.y;
            o.w = o.z + v.z;
            ((int4*)offs)[i4] = o;
            ((int4*)cursor)[i4] = o;
        }
        carry += tot;
        __syncthreads();
    }
    if (t == 0) offs[NNODE] = NEDGE;
}

// ---- fused per-node attention: 4-edge batched online softmax ----
__global__ __launch_bounds__(256) void k_node(const u16* __restrict__ QB,
        const float* __restrict__ SkipF, const int* __restrict__ offs,
        const int* __restrict__ sorted, const int* __restrict__ eidx,
        const int* __restrict__ edge_ids, const float* __restrict__ last_update,
        const float* __restrict__ time_w, const float* __restrict__ time_b,
        const float* __restrict__ ef, const int* __restrict__ tptr,
        float* __restrict__ out, u16* __restrict__ saccb) {
    int wave = threadIdx.x >> 6, lane = threadIdx.x & 63;
    int n = blockIdx.x * 4 + wave;
    int c = 2 * lane;
    const u16* rowq = QB + (size_t)n * 768;
    unsigned qw  = *(const unsigned*)(rowq + c);
    unsigned qtw = *(const unsigned*)(rowq + 512 + c);
    unsigned qfw = *(const unsigned*)(rowq + 640 + c);
    float2 qd, qet, qef;
    qd.x  = b2f(qw & 0xffffu);  qd.y  = b2f(qw >> 16);
    qet.x = b2f(qtw & 0xffffu); qet.y = b2f(qtw >> 16);
    qef.x = b2f(qfw & 0xffffu); qef.y = b2f(qfw >> 16);
    float2 skip = *(const float2*)(SkipF + (size_t)n * HID + c);
    float2 tw   = *(const float2*)(time_w + c);
    float2 tb   = *(const float2*)(time_b + c);
    float tf = (float)(*tptr);
    int start = offs[n], end = offs[n + 1];
    int deg = end - start;
    if (deg == 0) {
        *(float2*)(out + (size_t)n * HID + c) = skip;
        *(unsigned*)(saccb + (size_t)n * 256 + c) = 0u;
        *(unsigned*)(saccb + (size_t)n * 256 + 128 + c) = 0u;
        return;
    }
    float m = -1e30f, l_ = 0.f;
    float va0 = 0.f, va1 = 0.f, s00 = 0.f, s01 = 0.f, s10 = 0.f, s11 = 0.f;
    for (int cb = start; cb < end; cb += 64) {
        int cnt = end - cb; if (cnt > 64) cnt = 64;
        int s_l = 0, eid_l = 0; float rt_l = 0.f;
        if (lane < cnt) {
            int j = sorted[cb + lane];
            s_l = eidx[j];
            eid_l = edge_ids[j];
            rt_l = tf - last_update[eid_l];
        }
        for (int e0 = 0; e0 < cnt; e0 += 4) {
            float pv[4], cv0[4], cv1[4], vx[4], vy[4], ex[4], ey[4];
#pragma unroll
            for (int i = 0; i < 4; ++i) {
                int idx = e0 + i;
                int sel = (idx < cnt) ? idx : e0;
                int s   = __shfl(s_l, sel, 64);
                int eid = __shfl(eid_l, sel, 64);
                float rt = __shfl(rt_l, sel, 64);
                unsigned kvp = *(const unsigned*)(QB + (size_t)s * 768 + 128 + c);
                unsigned vvp = *(const unsigned*)(QB + (size_t)s * 768 + 256 + c);
                float2 ev = *(const float2*)(ef + (size_t)eid * HID + c);
                float k0f = b2f(kvp & 0xffffu), k1f = b2f(kvp >> 16);
                vx[i] = b2f(vvp & 0xffffu); vy[i] = b2f(vvp >> 16);
                cv0[i] = __cosf(rt * tw.x + tb.x);
                cv1[i] = __cosf(rt * tw.y + tb.y);
                ex[i] = ev.x; ey[i] = ev.y;
                pv[i] = qd.x * k0f + qd.y * k1f + qet.x * cv0[i] + qet.y * cv1[i]
                      + qef.x * ev.x + qef.y * ev.y;
            }
#pragma unroll
            for (int msk = 32; msk > 0; msk >>= 1) {
#pragma unroll
                for (int i = 0; i < 4; ++i) pv[i] += __shfl_xor(pv[i], msk, 64);
            }
            float al[4];
#pragma unroll
            for (int i = 0; i < 4; ++i)
                al[i] = (e0 + i < cnt) ? pv[i] * 0.08838834764831845f : -1e30f;
            float gm = fmaxf(fmaxf(al[0], al[1]), fmaxf(al[2], al[3]));
            if (gm > m) {
                float fac = __expf(m - gm);
                l_ *= fac; va0 *= fac; va1 *= fac;
                s00 *= fac; s01 *= fac; s10 *= fac; s11 *= fac;
                m = gm;
            }
#pragma unroll
            for (int i = 0; i < 4; ++i) {
                float w = __expf(al[i] - m);
                l_ += w;
                va0 += w * vx[i]; va1 += w * vy[i];
                s00 += w * cv0[i]; s01 += w * cv1[i];
                s10 += w * ex[i]; s11 += w * ey[i];
            }
        }
    }
    float inv = 1.f / fmaxf(l_, 1e-16f);
    float2 o; o.x = va0 * inv + skip.x; o.y = va1 * inv + skip.y;
    *(float2*)(out + (size_t)n * HID + c) = o;
    unsigned p0 = (unsigned)f2b(s00 * inv) | ((unsigned)f2b(s01 * inv) << 16);
    unsigned p1 = (unsigned)f2b(s10 * inv) | ((unsigned)f2b(s11 * inv) << 16);
    *(unsigned*)(saccb + (size_t)n * 256 + c) = p0;
    *(unsigned*)(saccb + (size_t)n * 256 + 128 + c) = p1;
}

extern "C" void kernel_launch(void* const* d_in, const int* in_sizes, int n_in,
                              void* d_out, int out_size, void* d_ws, size_t ws_size,
                              hipStream_t stream) {
    const int*   et_ids        = (const int*)d_in[0];
    const int*   src_ids       = (const int*)d_in[1];
    const float* src_mask      = (const float*)d_in[2];
    const int*   dst_ids       = (const int*)d_in[3];
    const float* dst_mask      = (const float*)d_in[4];
    const int*   ev_eids       = (const int*)d_in[5];
    const float* ev_emb        = (const float*)d_in[6];
    const float* ev_mask       = (const float*)d_in[7];
    const float* ev_ts         = (const float*)d_in[8];
    const int*   node_ids      = (const int*)d_in[9];
    const int*   edge_ids      = (const int*)d_in[10];
    const int*   edge_index    = (const int*)d_in[11];
    const int*   tptr          = (const int*)d_in[12];
    float*       memory        = (float*)d_in[13];
    const float* last_update   = (const float*)d_in[14];
    const float* node_features = (const float*)d_in[15];
    const float* edge_features = (const float*)d_in[16];
    const float* time_w        = (const float*)d_in[17];
    const float* time_b        = (const float*)d_in[18];
    const float* w_ih          = (const float*)d_in[19];
    const float* w_hh          = (const float*)d_in[20];
    const float* b_ih          = (const float*)d_in[21];
    const float* b_hh          = (const float*)d_in[22];
    const float* wq            = (const float*)d_in[23];
    const float* bq            = (const float*)d_in[24];
    const float* wk            = (const float*)d_in[25];
    const float* bk            = (const float*)d_in[26];
    const float* wv            = (const float*)d_in[27];
    const float* bv            = (const float*)d_in[28];
    const float* we            = (const float*)d_in[29];
    const float* wskip         = (const float*)d_in[30];
    const float* bskip         = (const float*)d_in[31];
    float* out = (float*)d_out;
    char*  wsb = (char*)d_ws;

    u16*   Wcatb    = (u16*)(wsb + OFF_WCATB);
    u16*   we_b     = (u16*)(wsb + OFF_WEB);
    u16*   Wallb    = (u16*)(wsb + OFF_WALLB);
    float* ball     = (float*)(wsb + OFF_BALL);
    int*   head_src = (int*)(wsb + OFF_HEAD_SRC);
    int*   head_dst = (int*)(wsb + OFF_HEAD_DST);
    int*   cnt_src  = (int*)(wsb + OFF_CNT_SRC);
    int*   cnt_dst  = (int*)(wsb + OFF_CNT_DST);
    int*   chain_src= (int*)(wsb + OFF_CHAIN_SRC);
    int*   chain_dst= (int*)(wsb + OFF_CHAIN_DST);
    u16*   XHb      = (u16*)(wsb + OFF_XHB);
    float* Hg       = (float*)(wsb + OFF_HG);
    float* Grz      = (float*)(wsb + OFF_GRZ);
    float* Gin      = (float*)(wsb + OFF_GIN);
    float* Ghn      = (float*)(wsb + OFF_GHN);
    u16*   Xb       = (u16*)(wsb + OFF_XB);
    u16*   QB       = (u16*)(wsb + OFF_QB);
    float* SkipF    = (float*)(wsb + OFF_SKIPF);
    int*   deg      = (int*)(wsb + OFF_DEG);
    int*   offs     = (int*)(wsb + OFF_OFFS);
    int*   cursor   = (int*)(wsb + OFF_CURSOR);
    int*   sorted   = (int*)(wsb + OFF_SORTED);
    u16*   saccb    = (u16*)(wsb + OFF_SACCB);

    // 1: weight prep + deg zero + table clears
    k_prep<<<2000, 256, 0, stream>>>(w_ih, w_hh, we, wq, wk, wv, wskip, bq, bk, bv, bskip,
                                     Wcatb, we_b, Wallb, ball, deg, wsb + OFF_HEAD_SRC);
    // 2: messages + tables/chains + deg hist
    k_msg_tables<<<6628, 128, 0, stream>>>(et_ids, src_ids, src_mask, dst_ids, dst_mask, ev_eids,
                                           ev_emb, ev_mask, ev_ts, memory, last_update, time_w, time_b,
                                           head_src, head_dst, cnt_src, cnt_dst, chain_src, chain_dst,
                                           edge_index, deg, XHb, Hg);
    // 3: dup-group mean fixup
    k_fix<<<2 * EVT, 128, 0, stream>>>(src_ids, dst_ids, head_src, head_dst, chain_src, chain_dst,
                                       cnt_src, cnt_dst, et_ids, src_mask, dst_mask, ev_eids,
                                       ev_emb, ev_mask, ev_ts, memory, last_update, time_w, time_b,
                                       XHb);
    // 4: gates GEMM (192 blocks: 64 m-strips x 3 gates, gi+gh per block)
    k_gemm_gates<<<dim3(64, 3), 256, 0, stream>>>(XHb, Wcatb, b_ih, b_hh, Grz, Gin, Ghn);
    // 5: GRU combine + memory scatter
    k_gru_scatter<<<2 * EVT, 128, 0, stream>>>(Grz, Gin, Ghn, Hg, src_ids, dst_ids, cnt_dst, memory);
    // 6: node features + degree scan
    k_x_scan<<<2501, 1024, 0, stream>>>(node_ids, node_features, memory, Xb, deg, offs, cursor);
    // 7: QKVSE GEMM (bf16 QB + f32 skip) + sortscat slice
    k_gemm_qkvse<<<dim3(157, 7), 256, 0, stream>>>(Xb, Wallb, ball, QB, SkipF,
                                                   edge_index, cursor, sorted);
    // 8: per-node attention
    k_node<<<NNODE / 4, 256, 0, stream>>>(QB, SkipF, offs, sorted, edge_index, edge_ids,
                                          last_update, time_w, time_b, edge_features, tptr,
                                          out, saccb);
    // 9: final edge-feature GEMM (accumulate into out)
    k_gemm_mfma<<<dim3(157, 1), 256, 0, stream>>>(saccb, we_b, nullptr, out, NNODE, 128, 256, 1);
}

// Round 6
// 473.703 us; speedup vs baseline: 1.1360x; 1.0151x over previous
//
#include <hip/hip_runtime.h>
#include <math.h>

#define HID   128
#define MAXN  100000
#define MAXE  300000
#define EVT   4096
#define NNODE 20000
#define NEDGE 320000

typedef unsigned short u16;
typedef __attribute__((ext_vector_type(8))) short bf16x8;
typedef __attribute__((ext_vector_type(4))) float f32x4;

// ---------------- workspace layout (bytes) ----------------
// PERSIST (weights)
#define OFF_WCATB     0u                    // 384*768 bf16 = 589824  ([w_ih | w_hh] concat)
#define OFF_WEB       589824u               // 128*256 bf16 = 65536
#define OFF_WALLB     655360u               // 640*128 bf16 = 163840 (q|k|v|qe -- skip removed)
#define OFF_BALL      819200u               // 640 f32 = 2560
#define OFF_WSKIPB    821760u               // 128*128 bf16 = 32768 (ends 854528 < BASE2)
#define BASE2         855040u
// EVENT arena
#define OFF_HEAD_SRC  (BASE2 + 0u)          // MAXN i32 (0xFF init)
#define OFF_HEAD_DST  (BASE2 + 400128u)     // MAXN i32 (0xFF init)
#define OFF_CNT_SRC   (BASE2 + 800256u)     // MAXN i32 (0 init)
#define OFF_CNT_DST   (BASE2 + 1200384u)    // MAXN i32 (0 init)
#define OFF_CHAIN_SRC (BASE2 + 1600512u)    // EVT i32
#define OFF_CHAIN_DST (BASE2 + 1616896u)    // EVT i32
#define OFF_XHB       (BASE2 + 1703936u)    // 8192*768 bf16 = 12582912
#define OFF_HG        (BASE2 + 14286848u)   // 8192*128 f32 = 4194304
// GATE buffers (dead after k_gru_scatter; alias NODE arena written later)
#define OFF_GRZ       (BASE2 + 20000000u)   // 8192*256 f32 = 8388608
#define OFF_GIN       (BASE2 + 28388608u)   // 8192*128 f32 = 4194304
#define OFF_GHN       (BASE2 + 32582912u)   // 8192*128 f32 = 4194304
// NODE arena (written AFTER gate buffers are dead -- stream-ordered, safe)
#define OFF_XB        (BASE2 + 20000000u)   // 20000*128 bf16 = 5120000
#define OFF_QB        (BASE2 + 25120000u)   // 20000*640 bf16 = 25600000 (q|k|v|qe)
#define OFF_DEG       (BASE2 + 66080000u)   // 20000 i32
#define OFF_OFFS      (BASE2 + 66160128u)   // 20001 i32
#define OFF_CURSOR    (BASE2 + 66240256u)   // 20000 i32
#define OFF_SORTED    (BASE2 + 66320384u)   // 320000 i32
#define OFF_SACCB     (BASE2 + 67600384u)   // 20000*256 bf16 = 10240000
// peak ~78.5 MB

__device__ __forceinline__ float sigmoidf_(float x) { return 1.f / (1.f + __expf(-x)); }
__device__ __forceinline__ u16 f2b(float f) {
    unsigned u = __float_as_uint(f);
    unsigned r = (u + 0x7fffu + ((u >> 16) & 1u)) >> 16;
    return (u16)r;
}
__device__ __forceinline__ float b2f(unsigned h) { return __uint_as_float(h << 16); }

// ---- fused weight prep: Wcat + we + deg zero + Wall(640) + wskip + table clears ----
// sections: [0,1152) Wcat | [1152,1280) we | [1280,1359) deg | [1359,1679) Wall |
//           [1679,1743) wskipb | [1743,2000) clears (grid-stride, 257 blocks)
__global__ void k_prep(const float* __restrict__ w_ih, const float* __restrict__ w_hh,
                       const float* __restrict__ we,
                       const float* __restrict__ wq, const float* __restrict__ wk_,
                       const float* __restrict__ wv, const float* __restrict__ wskip,
                       const float* __restrict__ bq, const float* __restrict__ bk,
                       const float* __restrict__ bv,
                       u16* __restrict__ Wcatb, u16* __restrict__ we_b,
                       u16* __restrict__ Wallb, float* __restrict__ ball,
                       u16* __restrict__ wskipb,
                       int* __restrict__ deg, char* __restrict__ zbase) {
    int b = blockIdx.x, t = threadIdx.x;
    if (b < 1152) {                     // Wcat: 384 rows x 768 cols
        int idx = b * 256 + t;
        int row = idx / 768, col = idx % 768;
        float v = (col < 640) ? w_ih[row * 640 + col] : w_hh[row * 128 + (col - 640)];
        Wcatb[idx] = f2b(v);
        return;
    }
    b -= 1152;
    if (b < 128) {                      // we: 128*256
        int i = b * 256 + t;
        we_b[i] = f2b(we[i]);
        return;
    }
    b -= 128;
    if (b < 79) {                       // deg zero
        int i = b * 256 + t;
        if (i < NNODE) deg[i] = 0;
        return;
    }
    b -= 79;
    if (b < 320) {                      // Wall build: 640*128 (q|k|v|qe)
        int idx = b * 256 + t;
        int row = idx >> 7;
        int k = idx & 127;
        float v;
        if (row < 128)      v = wq[row * 128 + k];
        else if (row < 256) v = wk_[(row - 128) * 128 + k];
        else if (row < 384) v = wv[(row - 256) * 128 + k];
        else {
            int j = row - 384;
            float a = 0.f;
            for (int t2 = 0; t2 < 128; t2++) a += wq[t2 * 128 + k] * we[t2 * 256 + j];
            v = a;
        }
        Wallb[row * 128 + k] = f2b(v);
        if (k == 0) {
            float bb;
            if (row < 128)      bb = bq[row];
            else if (row < 256) bb = bk[row - 128];
            else if (row < 384) bb = bv[row - 256];
            else { int j = row - 384; float a = 0.f; for (int t2 = 0; t2 < 128; t2++) a += bq[t2] * we[t2 * 256 + j]; bb = a; }
            ball[row] = bb;
        }
        return;
    }
    b -= 320;
    if (b < 64) {                       // wskip bf16: 128*128
        int i = b * 256 + t;
        wskipb[i] = f2b(wskip[i]);
        return;
    }
    b -= 64;
    // table clears: heads (0xFF, 800256 B) then cnts (0, 800256 B), 16B chunks
    const int NFF = 50016;     // 800256/16
    uint4 ff = make_uint4(0xFFFFFFFFu, 0xFFFFFFFFu, 0xFFFFFFFFu, 0xFFFFFFFFu);
    uint4 zz = make_uint4(0u, 0u, 0u, 0u);
    int idx = b * 256 + t;
    int stride = 257 * 256;
    uint4* pff = (uint4*)zbase;
    uint4* pzz = (uint4*)(zbase + 800256);
    for (int i = idx; i < NFF; i += stride) pff[i] = ff;
    for (int i = idx; i < NFF; i += stride) pzz[i] = zz;
}

// ---- fused: messages (direct XHb/Hg write) + id tables/chains + dst-deg hist ----
__global__ void k_msg_tables(const int* __restrict__ et_ids, const int* __restrict__ src_ids,
                          const float* __restrict__ src_mask, const int* __restrict__ dst_ids,
                          const float* __restrict__ dst_mask, const int* __restrict__ ev_eids,
                          const float* __restrict__ ev_emb, const float* __restrict__ ev_mask,
                          const float* __restrict__ ev_ts, const float* __restrict__ memory,
                          const float* __restrict__ last_update, const float* __restrict__ time_w,
                          const float* __restrict__ time_b,
                          int* __restrict__ head_src, int* __restrict__ head_dst,
                          int* __restrict__ cnt_src, int* __restrict__ cnt_dst,
                          int* __restrict__ chain_src, int* __restrict__ chain_dst,
                          const int* __restrict__ eidx, int* __restrict__ deg,
                          u16* __restrict__ XHb, float* __restrict__ Hg) {
    int b = blockIdx.x, t = threadIdx.x;
    if (b >= EVT) {
        int bb = b - EVT;
        if (bb < 32) {                       // tables: 4096 events
            int i = bb * 128 + t;
            int s = src_ids[i], d = dst_ids[i];
            chain_src[i] = atomicExch(&head_src[s], i);
            atomicAdd(&cnt_src[s], 1);
            chain_dst[i] = atomicExch(&head_dst[d], i);
            atomicAdd(&cnt_dst[d], 1);
        } else {                             // deg hist: 320000 edges
            int j = (bb - 32) * 128 + t;
            atomicAdd(&deg[eidx[NEDGE + j]], 1);
        }
        return;
    }
    int i = b;
    int c = t;
    int et = et_ids[i];
    float sm = src_mask[i], dm = dst_mask[i], em = ev_mask[i], ts = ev_ts[i];
    int sid = src_ids[i], did = dst_ids[i], eid = ev_eids[i];
    float isnode = (et == 3 || et == 4) ? 1.f : 0.f;
    float rel = ts - last_update[eid] * dm;
    float tval = ts * isnode + rel * dm;
    float tse = __cosf(tval * time_w[c] + time_b[c]) * em;
    float typ = (float)et;
    float sv_raw = memory[(size_t)sid * HID + c];
    float dv_raw = memory[(size_t)did * HID + c];
    float sv = sv_raw * sm;
    float dv = dv_raw * dm;
    float ev = ev_emb[(size_t)i * HID + c];
    Hg[(size_t)i * HID + c] = sv_raw;
    Hg[(size_t)(EVT + i) * HID + c] = dv_raw;
    u16* xs = XHb + (size_t)i * 768;
    xs[c] = f2b(typ * em); xs[128 + c] = f2b(sv * em); xs[256 + c] = f2b(dv * em);
    xs[384 + c] = f2b(tse * em); xs[512 + c] = f2b(ev * em);
    xs[640 + c] = f2b(sv_raw);
    u16* xd = XHb + (size_t)(EVT + i) * 768;
    xd[c] = f2b(typ * dm); xd[128 + c] = f2b(dv * dm); xd[256 + c] = f2b(sv * dm);
    xd[384 + c] = f2b(tse * dm); xd[512 + c] = f2b(ev * dm);
    xd[640 + c] = f2b(dv_raw);
}

// ---- fixup: rows whose id has cnt>1 recompute the group mean via chain walk ----
__global__ void k_fix(const int* __restrict__ src_ids, const int* __restrict__ dst_ids,
                      const int* __restrict__ head_src, const int* __restrict__ head_dst,
                      const int* __restrict__ chain_src, const int* __restrict__ chain_dst,
                      const int* __restrict__ cnt_src, const int* __restrict__ cnt_dst,
                      const int* __restrict__ et_ids, const float* __restrict__ src_mask,
                      const float* __restrict__ dst_mask, const int* __restrict__ ev_eids,
                      const float* __restrict__ ev_emb, const float* __restrict__ ev_mask,
                      const float* __restrict__ ev_ts, const float* __restrict__ memory,
                      const float* __restrict__ last_update, const float* __restrict__ time_w,
                      const float* __restrict__ time_b, u16* __restrict__ XHb) {
    int r = blockIdx.x, c = threadIdx.x;
    bool is_src = (r < EVT);
    int id = is_src ? src_ids[r] : dst_ids[r - EVT];
    int cnt = is_src ? cnt_src[id] : cnt_dst[id];
    if (cnt < 2) return;
    float own = memory[(size_t)id * HID + c];
    float tw = time_w[c], tb = time_b[c];
    float a0 = 0.f, a1 = 0.f, a2 = 0.f, a3 = 0.f, a4 = 0.f;
    int j = is_src ? head_src[id] : head_dst[id];
    for (int k = 0; k < cnt; ++k) {
        int et = et_ids[j];
        float sm = src_mask[j], dm = dst_mask[j], em = ev_mask[j], ts = ev_ts[j];
        int eid = ev_eids[j];
        float isnode = (et == 3 || et == 4) ? 1.f : 0.f;
        float rel = ts - last_update[eid] * dm;
        float tval = ts * isnode + rel * dm;
        float tse = __cosf(tval * tw + tb);
        float ev = ev_emb[(size_t)j * HID + c];
        float typ = (float)et;
        if (is_src) {
            float sv = own * sm;
            float dv = memory[(size_t)dst_ids[j] * HID + c] * dm;
            float tsm = tse * em;
            a0 += typ * em; a1 += sv * em; a2 += dv * em;
            a3 += tsm * em; a4 += ev * em;
            j = chain_src[j];
        } else {
            float dv = own * dm;
            float sv = memory[(size_t)src_ids[j] * HID + c] * sm;
            float tsm = tse * em;
            a0 += typ * dm; a1 += dv * dm; a2 += sv * dm;
            a3 += tsm * dm; a4 += ev * dm;
            j = chain_dst[j];
        }
    }
    float inv = 1.f / (float)cnt;
    u16* x = XHb + (size_t)r * 768;
    x[c] = f2b(a0 * inv); x[128 + c] = f2b(a1 * inv); x[256 + c] = f2b(a2 * inv);
    x[384 + c] = f2b(a3 * inv); x[512 + c] = f2b(a4 * inv);
}

// ---- shared MFMA K-pass: acc += A[128 strip, K] @ W[128 rows, K]^T (strided) ----
__device__ __forceinline__ void gate_pass(const u16* __restrict__ A, int lda,
                                          const u16* __restrict__ W, int ldw, int K,
                                          f32x4 acc[4][4], u16* Als, u16* Wls,
                                          int bm, int wm, int wn, int l15, int quad, int tid) {
    for (int k0 = 0; k0 < K; k0 += 32) {
#pragma unroll
        for (int h = 0; h < 2; ++h) {
            int ch = tid + h * 256;
            int row = ch >> 2, kc = (ch & 3) * 8;
            *(float4*)&Als[row * 40 + kc] = *(const float4*)(A + (size_t)(bm + row) * lda + k0 + kc);
            *(float4*)&Wls[row * 40 + kc] = *(const float4*)(W + (size_t)row * ldw + k0 + kc);
        }
        __syncthreads();
        bf16x8 af[4], bfr[4];
#pragma unroll
        for (int r = 0; r < 4; ++r)
            af[r] = *(const bf16x8*)&Als[(wm + r * 16 + l15) * 40 + quad * 8];
#pragma unroll
        for (int c2 = 0; c2 < 4; ++c2)
            bfr[c2] = *(const bf16x8*)&Wls[(wn + c2 * 16 + l15) * 40 + quad * 8];
#pragma unroll
        for (int r = 0; r < 4; ++r)
#pragma unroll
            for (int c2 = 0; c2 < 4; ++c2)
                acc[r][c2] = __builtin_amdgcn_mfma_f32_16x16x32_bf16(af[r], bfr[c2], acc[r][c2], 0, 0, 0);
        __syncthreads();
    }
}

// ---- gates GEMM: grid (64 m-strips, 3 gates) ----
__global__ __launch_bounds__(256) void k_gemm_gates(const u16* __restrict__ XHb,
        const u16* __restrict__ Wcat, const float* __restrict__ b_ih,
        const float* __restrict__ b_hh, float* __restrict__ Grz,
        float* __restrict__ Gin, float* __restrict__ Ghn) {
    __shared__ u16 Als[128 * 40];
    __shared__ u16 Wls[128 * 40];
    int tid = threadIdx.x;
    int bm = blockIdx.x * 128;
    int g = blockIdx.y;
    int wave = tid >> 6, lane = tid & 63;
    int wm = (wave & 1) * 64, wn = (wave >> 1) * 64;
    int l15 = lane & 15, quad = lane >> 4;
    f32x4 acc_i[4][4] = {};
    f32x4 acc_h[4][4] = {};
    const u16* Wg = Wcat + (size_t)(g * 128) * 768;
    gate_pass(XHb, 768, Wg, 768, 640, acc_i, Als, Wls, bm, wm, wn, l15, quad, tid);
    gate_pass(XHb + 640, 768, Wg + 640, 768, 128, acc_h, Als, Wls, bm, wm, wn, l15, quad, tid);
#pragma unroll
    for (int r = 0; r < 4; ++r) {
#pragma unroll
        for (int c2 = 0; c2 < 4; ++c2) {
            int ncol = wn + c2 * 16 + l15;
            float bi = b_ih[g * 128 + ncol];
            float bh = b_hh[g * 128 + ncol];
#pragma unroll
            for (int reg = 0; reg < 4; ++reg) {
                int mrow = bm + wm + r * 16 + quad * 4 + reg;
                if (g < 2) {
                    Grz[(size_t)mrow * 256 + g * 128 + ncol] =
                        acc_i[r][c2][reg] + acc_h[r][c2][reg] + bi + bh;
                } else {
                    Gin[(size_t)mrow * 128 + ncol] = acc_i[r][c2][reg] + bi;
                    Ghn[(size_t)mrow * 128 + ncol] = acc_h[r][c2][reg] + bh;
                }
            }
        }
    }
}

// ---- GRU gate combine + scatter-to-memory (dst overrides src) ----
__global__ void k_gru_scatter(const float* __restrict__ Grz, const float* __restrict__ Gin,
                              const float* __restrict__ Ghn, const float* __restrict__ Hg,
                              const int* __restrict__ src_ids, const int* __restrict__ dst_ids,
                              const int* __restrict__ cnt_dst, float* __restrict__ memory) {
    int r = blockIdx.x, c = threadIdx.x;
    float rg = sigmoidf_(Grz[(size_t)r * 256 + c]);
    float z  = sigmoidf_(Grz[(size_t)r * 256 + 128 + c]);
    float n  = tanhf(Gin[(size_t)r * 128 + c] + rg * Ghn[(size_t)r * 128 + c]);
    float h0 = Hg[(size_t)r * HID + c];
    float h  = (1.f - z) * n + z * h0;
    if (r < EVT) {
        int sid = src_ids[r];
        if (cnt_dst[sid] == 0) memory[(size_t)sid * HID + c] = h;
    } else {
        int did = dst_ids[r - EVT];
        memory[(size_t)did * HID + c] = h;
    }
}

// ---- QKVSE GEMM: bf16 QB (640 cols: q|k|v|qe) + sortscat slice (y==5) ----
__global__ __launch_bounds__(256) void k_gemm_qkvse(const u16* __restrict__ A,
                                                    const u16* __restrict__ W,
                                                    const float* __restrict__ bias,
                                                    u16* __restrict__ QB,
                                                    const int* __restrict__ eidx,
                                                    int* __restrict__ cursor,
                                                    int* __restrict__ sorted) {
    __shared__ u16 Als[128 * 40];
    __shared__ u16 Wls[128 * 40];
    if (blockIdx.y == 5) {
        int j = blockIdx.x * 256 + threadIdx.x;
        for (; j < NEDGE; j += 157 * 256) {
            int d = eidx[NEDGE + j];
            int pos = atomicAdd(&cursor[d], 1);
            sorted[pos] = j;
        }
        return;
    }
    int tid = threadIdx.x;
    int bm = blockIdx.x * 128, bn = blockIdx.y * 128;
    int wave = tid >> 6, lane = tid & 63;
    int wm = (wave & 1) * 64, wn = (wave >> 1) * 64;
    int l15 = lane & 15, quad = lane >> 4;
    f32x4 accf[4][4] = {};
    for (int k0 = 0; k0 < 128; k0 += 32) {
#pragma unroll
        for (int h = 0; h < 2; ++h) {
            int ch = tid + h * 256;
            int row = ch >> 2, kc = (ch & 3) * 8;
            int gr = bm + row;
            float4 av = make_float4(0.f, 0.f, 0.f, 0.f);
            if (gr < NNODE) av = *(const float4*)(A + (size_t)gr * 128 + k0 + kc);
            *(float4*)&Als[row * 40 + kc] = av;
            int wr = bn + row;
            float4 wv_ = *(const float4*)(W + (size_t)wr * 128 + k0 + kc);
            *(float4*)&Wls[row * 40 + kc] = wv_;
        }
        __syncthreads();
        bf16x8 af[4], bfr[4];
#pragma unroll
        for (int r = 0; r < 4; ++r)
            af[r] = *(const bf16x8*)&Als[(wm + r * 16 + l15) * 40 + quad * 8];
#pragma unroll
        for (int c2 = 0; c2 < 4; ++c2)
            bfr[c2] = *(const bf16x8*)&Wls[(wn + c2 * 16 + l15) * 40 + quad * 8];
#pragma unroll
        for (int r = 0; r < 4; ++r)
#pragma unroll
            for (int c2 = 0; c2 < 4; ++c2)
                accf[r][c2] = __builtin_amdgcn_mfma_f32_16x16x32_bf16(af[r], bfr[c2], accf[r][c2], 0, 0, 0);
        __syncthreads();
    }
#pragma unroll
    for (int r = 0; r < 4; ++r) {
#pragma unroll
        for (int c2 = 0; c2 < 4; ++c2) {
            int ncol = bn + wn + c2 * 16 + l15;
            float bv = bias[ncol];
#pragma unroll
            for (int reg = 0; reg < 4; ++reg) {
                int mrow = bm + wm + r * 16 + quad * 4 + reg;
                if (mrow >= NNODE) continue;
                QB[(size_t)mrow * 640 + ncol] = f2b(accf[r][c2][reg] + bv);
            }
        }
    }
}

// ---- node-feature build (blocks 0..2499, 8 rows each) + degree scan (block 2500) ----
__global__ __launch_bounds__(1024) void k_x_scan(const int* __restrict__ node_ids,
                                                 const float* __restrict__ nf,
                                                 const float* __restrict__ memory,
                                                 u16* __restrict__ Xb,
                                                 const int* __restrict__ deg,
                                                 int* __restrict__ offs,
                                                 int* __restrict__ cursor) {
    __shared__ int wsum[16];
    int p = blockIdx.x, t = threadIdx.x;
    if (p < 2500) {
        int row = p * 8 + (t >> 7), c = t & 127;
        int nid = node_ids[row];
        Xb[(size_t)row * HID + c] = f2b(nf[(size_t)nid * HID + c] + memory[(size_t)nid * HID + c]);
        return;
    }
    int lane = t & 63, w = t >> 6;
    int carry = 0;
    const int N4 = NNODE / 4;   // 5000
    for (int base = 0; base < N4; base += 1024) {
        int i4 = base + t;
        int4 v = make_int4(0, 0, 0, 0);
        if (i4 < N4) v = ((const int4*)deg)[i4];
        int s = v.x + v.y + v.z + v.w;
        int x = s;
#pragma unroll
        for (int d = 1; d < 64; d <<= 1) { int y = __shfl_up(x, d, 64); if (lane >= d) x += y; }
        if (lane == 63) wsum[w] = x;
        __syncthreads();
        int add = 0, tot = 0;
        for (int k2 = 0; k2 < 16; ++k2) { int ss = wsum[k2]; if (k2 < w) add += ss; tot += ss; }
        if (i4 < N4) {
            int e = carry + add + x - s;
            int4 o;
            o.x = e;
            o.y = e + v.x;
            o.z = o.y + v.y;
            o.w = o.z + v.z;
            ((int4*)offs)[i4] = o;
            ((int4*)cursor)[i4] = o;
        }
        carry += tot;
        __syncthreads();
    }
    if (t == 0) offs[NNODE] = NEDGE;
}

// ---- fused per-node attention: writes attention part only (no skip) ----
__global__ __launch_bounds__(256) void k_node(const u16* __restrict__ QB,
        const int* __restrict__ offs,
        const int* __restrict__ sorted, const int* __restrict__ eidx,
        const int* __restrict__ edge_ids, const float* __restrict__ last_update,
        const float* __restrict__ time_w, const float* __restrict__ time_b,
        const float* __restrict__ ef, const int* __restrict__ tptr,
        float* __restrict__ out, u16* __restrict__ saccb) {
    int wave = threadIdx.x >> 6, lane = threadIdx.x & 63;
    int n = blockIdx.x * 4 + wave;
    int c = 2 * lane;
    const u16* rowq = QB + (size_t)n * 640;
    unsigned qw  = *(const unsigned*)(rowq + c);
    unsigned qtw = *(const unsigned*)(rowq + 384 + c);
    unsigned qfw = *(const unsigned*)(rowq + 512 + c);
    float2 qd, qet, qef;
    qd.x  = b2f(qw & 0xffffu);  qd.y  = b2f(qw >> 16);
    qet.x = b2f(qtw & 0xffffu); qet.y = b2f(qtw >> 16);
    qef.x = b2f(qfw & 0xffffu); qef.y = b2f(qfw >> 16);
    float2 tw   = *(const float2*)(time_w + c);
    float2 tb   = *(const float2*)(time_b + c);
    float tf = (float)(*tptr);
    int start = offs[n], end = offs[n + 1];
    int deg = end - start;
    if (deg == 0) {
        float2 zz; zz.x = 0.f; zz.y = 0.f;
        *(float2*)(out + (size_t)n * HID + c) = zz;
        *(unsigned*)(saccb + (size_t)n * 256 + c) = 0u;
        *(unsigned*)(saccb + (size_t)n * 256 + 128 + c) = 0u;
        return;
    }
    float m = -1e30f, l_ = 0.f;
    float va0 = 0.f, va1 = 0.f, s00 = 0.f, s01 = 0.f, s10 = 0.f, s11 = 0.f;
    for (int cb = start; cb < end; cb += 64) {
        int cnt = end - cb; if (cnt > 64) cnt = 64;
        int s_l = 0, eid_l = 0; float rt_l = 0.f;
        if (lane < cnt) {
            int j = sorted[cb + lane];
            s_l = eidx[j];
            eid_l = edge_ids[j];
            rt_l = tf - last_update[eid_l];
        }
        for (int e0 = 0; e0 < cnt; e0 += 4) {
            float pv[4], cv0[4], cv1[4], vx[4], vy[4], ex[4], ey[4];
#pragma unroll
            for (int i = 0; i < 4; ++i) {
                int idx = e0 + i;
                int sel = (idx < cnt) ? idx : e0;
                int s   = __shfl(s_l, sel, 64);
                int eid = __shfl(eid_l, sel, 64);
                float rt = __shfl(rt_l, sel, 64);
                unsigned kvp = *(const unsigned*)(QB + (size_t)s * 640 + 128 + c);
                unsigned vvp = *(const unsigned*)(QB + (size_t)s * 640 + 256 + c);
                float2 ev = *(const float2*)(ef + (size_t)eid * HID + c);
                float k0f = b2f(kvp & 0xffffu), k1f = b2f(kvp >> 16);
                vx[i] = b2f(vvp & 0xffffu); vy[i] = b2f(vvp >> 16);
                cv0[i] = __cosf(rt * tw.x + tb.x);
                cv1[i] = __cosf(rt * tw.y + tb.y);
                ex[i] = ev.x; ey[i] = ev.y;
                pv[i] = qd.x * k0f + qd.y * k1f + qet.x * cv0[i] + qet.y * cv1[i]
                      + qef.x * ev.x + qef.y * ev.y;
            }
#pragma unroll
            for (int msk = 32; msk > 0; msk >>= 1) {
#pragma unroll
                for (int i = 0; i < 4; ++i) pv[i] += __shfl_xor(pv[i], msk, 64);
            }
            float al[4];
#pragma unroll
            for (int i = 0; i < 4; ++i)
                al[i] = (e0 + i < cnt) ? pv[i] * 0.08838834764831845f : -1e30f;
            float gm = fmaxf(fmaxf(al[0], al[1]), fmaxf(al[2], al[3]));
            if (gm > m) {
                float fac = __expf(m - gm);
                l_ *= fac; va0 *= fac; va1 *= fac;
                s00 *= fac; s01 *= fac; s10 *= fac; s11 *= fac;
                m = gm;
            }
#pragma unroll
            for (int i = 0; i < 4; ++i) {
                float w = __expf(al[i] - m);
                l_ += w;
                va0 += w * vx[i]; va1 += w * vy[i];
                s00 += w * cv0[i]; s01 += w * cv1[i];
                s10 += w * ex[i]; s11 += w * ey[i];
            }
        }
    }
    float inv = 1.f / fmaxf(l_, 1e-16f);
    float2 o; o.x = va0 * inv; o.y = va1 * inv;
    *(float2*)(out + (size_t)n * HID + c) = o;
    unsigned p0 = (unsigned)f2b(s00 * inv) | ((unsigned)f2b(s01 * inv) << 16);
    unsigned p1 = (unsigned)f2b(s10 * inv) | ((unsigned)f2b(s11 * inv) << 16);
    *(unsigned*)(saccb + (size_t)n * 256 + c) = p0;
    *(unsigned*)(saccb + (size_t)n * 256 + 128 + c) = p1;
}

// ---- final concat GEMM: out += saccb@we^T (K=256) + Xb@wskip^T (K=128) + bskip ----
__global__ __launch_bounds__(256) void k_final(const u16* __restrict__ saccb,
                                               const u16* __restrict__ Xb,
                                               const u16* __restrict__ web,
                                               const u16* __restrict__ wskipb,
                                               const float* __restrict__ bskip,
                                               float* __restrict__ out) {
    __shared__ u16 Als[128 * 40];
    __shared__ u16 Wls[128 * 40];
    int tid = threadIdx.x;
    int bm = blockIdx.x * 128;
    int wave = tid >> 6, lane = tid & 63;
    int wm = (wave & 1) * 64, wn = (wave >> 1) * 64;
    int l15 = lane & 15, quad = lane >> 4;
    f32x4 accf[4][4] = {};
#pragma unroll
    for (int pass = 0; pass < 2; ++pass) {
        const u16* A = pass ? Xb : saccb;
        const u16* W = pass ? wskipb : web;
        int lda = pass ? 128 : 256;
        int K = pass ? 128 : 256;
        for (int k0 = 0; k0 < K; k0 += 32) {
#pragma unroll
            for (int h = 0; h < 2; ++h) {
                int ch = tid + h * 256;
                int row = ch >> 2, kc = (ch & 3) * 8;
                int gr = bm + row;
                float4 av = make_float4(0.f, 0.f, 0.f, 0.f);
                if (gr < NNODE) av = *(const float4*)(A + (size_t)gr * lda + k0 + kc);
                *(float4*)&Als[row * 40 + kc] = av;
                *(float4*)&Wls[row * 40 + kc] = *(const float4*)(W + (size_t)row * lda + k0 + kc);
            }
            __syncthreads();
            bf16x8 af[4], bfr[4];
#pragma unroll
            for (int r = 0; r < 4; ++r)
                af[r] = *(const bf16x8*)&Als[(wm + r * 16 + l15) * 40 + quad * 8];
#pragma unroll
            for (int c2 = 0; c2 < 4; ++c2)
                bfr[c2] = *(const bf16x8*)&Wls[(wn + c2 * 16 + l15) * 40 + quad * 8];
#pragma unroll
            for (int r = 0; r < 4; ++r)
#pragma unroll
                for (int c2 = 0; c2 < 4; ++c2)
                    accf[r][c2] = __builtin_amdgcn_mfma_f32_16x16x32_bf16(af[r], bfr[c2], accf[r][c2], 0, 0, 0);
            __syncthreads();
        }
    }
#pragma unroll
    for (int r = 0; r < 4; ++r) {
#pragma unroll
        for (int c2 = 0; c2 < 4; ++c2) {
            int ncol = wn + c2 * 16 + l15;
            float bv = bskip[ncol];
#pragma unroll
            for (int reg = 0; reg < 4; ++reg) {
                int mrow = bm + wm + r * 16 + quad * 4 + reg;
                if (mrow >= NNODE) continue;
                out[(size_t)mrow * HID + ncol] += accf[r][c2][reg] + bv;
            }
        }
    }
}

extern "C" void kernel_launch(void* const* d_in, const int* in_sizes, int n_in,
                              void* d_out, int out_size, void* d_ws, size_t ws_size,
                              hipStream_t stream) {
    const int*   et_ids        = (const int*)d_in[0];
    const int*   src_ids       = (const int*)d_in[1];
    const float* src_mask      = (const float*)d_in[2];
    const int*   dst_ids       = (const int*)d_in[3];
    const float* dst_mask      = (const float*)d_in[4];
    const int*   ev_eids       = (const int*)d_in[5];
    const float* ev_emb        = (const float*)d_in[6];
    const float* ev_mask       = (const float*)d_in[7];
    const float* ev_ts         = (const float*)d_in[8];
    const int*   node_ids      = (const int*)d_in[9];
    const int*   edge_ids      = (const int*)d_in[10];
    const int*   edge_index    = (const int*)d_in[11];
    const int*   tptr          = (const int*)d_in[12];
    float*       memory        = (float*)d_in[13];
    const float* last_update   = (const float*)d_in[14];
    const float* node_features = (const float*)d_in[15];
    const float* edge_features = (const float*)d_in[16];
    const float* time_w        = (const float*)d_in[17];
    const float* time_b        = (const float*)d_in[18];
    const float* w_ih          = (const float*)d_in[19];
    const float* w_hh          = (const float*)d_in[20];
    const float* b_ih          = (const float*)d_in[21];
    const float* b_hh          = (const float*)d_in[22];
    const float* wq            = (const float*)d_in[23];
    const float* bq            = (const float*)d_in[24];
    const float* wk            = (const float*)d_in[25];
    const float* bk            = (const float*)d_in[26];
    const float* wv            = (const float*)d_in[27];
    const float* bv            = (const float*)d_in[28];
    const float* we            = (const float*)d_in[29];
    const float* wskip         = (const float*)d_in[30];
    const float* bskip         = (const float*)d_in[31];
    float* out = (float*)d_out;
    char*  wsb = (char*)d_ws;

    u16*   Wcatb    = (u16*)(wsb + OFF_WCATB);
    u16*   we_b     = (u16*)(wsb + OFF_WEB);
    u16*   Wallb    = (u16*)(wsb + OFF_WALLB);
    float* ball     = (float*)(wsb + OFF_BALL);
    u16*   wskipb   = (u16*)(wsb + OFF_WSKIPB);
    int*   head_src = (int*)(wsb + OFF_HEAD_SRC);
    int*   head_dst = (int*)(wsb + OFF_HEAD_DST);
    int*   cnt_src  = (int*)(wsb + OFF_CNT_SRC);
    int*   cnt_dst  = (int*)(wsb + OFF_CNT_DST);
    int*   chain_src= (int*)(wsb + OFF_CHAIN_SRC);
    int*   chain_dst= (int*)(wsb + OFF_CHAIN_DST);
    u16*   XHb      = (u16*)(wsb + OFF_XHB);
    float* Hg       = (float*)(wsb + OFF_HG);
    float* Grz      = (float*)(wsb + OFF_GRZ);
    float* Gin      = (float*)(wsb + OFF_GIN);
    float* Ghn      = (float*)(wsb + OFF_GHN);
    u16*   Xb       = (u16*)(wsb + OFF_XB);
    u16*   QB       = (u16*)(wsb + OFF_QB);
    int*   deg      = (int*)(wsb + OFF_DEG);
    int*   offs     = (int*)(wsb + OFF_OFFS);
    int*   cursor   = (int*)(wsb + OFF_CURSOR);
    int*   sorted   = (int*)(wsb + OFF_SORTED);
    u16*   saccb    = (u16*)(wsb + OFF_SACCB);

    // 1: weight prep + deg zero + table clears
    k_prep<<<2000, 256, 0, stream>>>(w_ih, w_hh, we, wq, wk, wv, wskip, bq, bk, bv,
                                     Wcatb, we_b, Wallb, ball, wskipb, deg, wsb + OFF_HEAD_SRC);
    // 2: messages + tables/chains + deg hist
    k_msg_tables<<<6628, 128, 0, stream>>>(et_ids, src_ids, src_mask, dst_ids, dst_mask, ev_eids,
                                           ev_emb, ev_mask, ev_ts, memory, last_update, time_w, time_b,
                                           head_src, head_dst, cnt_src, cnt_dst, chain_src, chain_dst,
                                           edge_index, deg, XHb, Hg);
    // 3: dup-group mean fixup
    k_fix<<<2 * EVT, 128, 0, stream>>>(src_ids, dst_ids, head_src, head_dst, chain_src, chain_dst,
                                       cnt_src, cnt_dst, et_ids, src_mask, dst_mask, ev_eids,
                                       ev_emb, ev_mask, ev_ts, memory, last_update, time_w, time_b,
                                       XHb);
    // 4: gates GEMM (192 blocks)
    k_gemm_gates<<<dim3(64, 3), 256, 0, stream>>>(XHb, Wcatb, b_ih, b_hh, Grz, Gin, Ghn);
    // 5: GRU combine + memory scatter
    k_gru_scatter<<<2 * EVT, 128, 0, stream>>>(Grz, Gin, Ghn, Hg, src_ids, dst_ids, cnt_dst, memory);
    // 6: node features + degree scan
    k_x_scan<<<2501, 1024, 0, stream>>>(node_ids, node_features, memory, Xb, deg, offs, cursor);
    // 7: QKVSE GEMM (bf16 QB, N=640) + sortscat slice
    k_gemm_qkvse<<<dim3(157, 6), 256, 0, stream>>>(Xb, Wallb, ball, QB,
                                                   edge_index, cursor, sorted);
    // 8: per-node attention (attention part only)
    k_node<<<NNODE / 4, 256, 0, stream>>>(QB, offs, sorted, edge_index, edge_ids,
                                          last_update, time_w, time_b, edge_features, tptr,
                                          out, saccb);
    // 9: final concat GEMM: out += sacc@we + x@wskip + bskip
    k_final<<<157, 256, 0, stream>>>(saccb, Xb, we_b, wskipb, bskip, out);
}